// Round 8
// baseline (1112.804 us; speedup 1.0000x reference)
//
#include <hip/hip_runtime.h>
#include <math.h>

#define BB 16
#define SS 64
#define NN 128
#define FF 16
#define HH 64
#define EE 1024
#define ET 1152   // EE + NN self-loops
#define LLAYERS 2
#define XPAD 65   // padded LDS row stride for gat_edge staging
#define RT (BB * SS * NN)   // 131072 GRU input rows

__device__ __forceinline__ float readlane_f(float v, int k) {
  return __int_as_float(__builtin_amdgcn_readlane(__float_as_int(v), k));
}
// monotonic float<->uint mapping for atomicMax-based float max
__device__ __forceinline__ unsigned flipf(float f) {
  unsigned u = __float_as_uint(f);
  unsigned mask = (u & 0x80000000u) ? 0xFFFFFFFFu : 0x80000000u;
  return u ^ mask;
}
__device__ __forceinline__ float unflipf(unsigned u) {
  unsigned b = (u & 0x80000000u) ? (u ^ 0x80000000u) : ~u;
  return __uint_as_float(b);
}
__device__ __forceinline__ float sigmoidf_(float x) { return 1.f / (1.f + expf(-x)); }

// ---------------- CSR setup (graph is identical for every (b,s)) -------------
__global__ void setup_csr_kernel(const int* __restrict__ ei,
                                 int* __restrict__ off,
                                 int* __restrict__ csrc,
                                 int* __restrict__ ctgt) {
  __shared__ int deg[NN], cur[NN], offs[NN + 1];
  int tid = threadIdx.x;
  if (tid < NN) deg[tid] = 0;
  __syncthreads();
  for (int e = tid; e < ET; e += 256) {
    int tg = (e < EE) ? ei[EE + e] : (e - EE);
    atomicAdd(&deg[tg], 1);
  }
  __syncthreads();
  if (tid == 0) {
    int s = 0;
    for (int i = 0; i < NN; ++i) { offs[i] = s; s += deg[i]; }
    offs[NN] = s;
  }
  __syncthreads();
  if (tid < NN) cur[tid] = offs[tid];
  if (tid <= NN) off[tid] = offs[tid];
  __syncthreads();
  for (int e = tid; e < ET; e += 256) {
    int sv, tg;
    if (e < EE) { sv = ei[e]; tg = ei[EE + e]; }
    else        { sv = e - EE; tg = e - EE; }
    int pos = atomicAdd(&cur[tg], 1);
    csrc[pos] = sv;
    ctgt[pos] = tg;
  }
}

// ---------------- input projection: h = x @ W^T + b --------------------------
__global__ __launch_bounds__(256) void input_proj_kernel(
    const float* __restrict__ x, const float* __restrict__ W,
    const float* __restrict__ bvec, float* __restrict__ h) {
  int lane = threadIdx.x & 63;
  int wid = threadIdx.x >> 6;
  float wreg[FF];
#pragma unroll
  for (int i = 0; i < FF / 4; ++i)
    *(float4*)&wreg[4 * i] = ((const float4*)(W + lane * FF))[i];
  float bias = bvec[lane];
  int row0 = __builtin_amdgcn_readfirstlane((blockIdx.x * 4 + wid) * 32);
#pragma unroll 2
  for (int r = 0; r < 32; ++r) {
    int row = row0 + r;
    const float* xr = x + row * FF;
    float acc = bias;
#pragma unroll
    for (int f = 0; f < FF; ++f) acc += xr[f] * wreg[f];
    h[row * HH + lane] = acc;
  }
}

// ---------------- GAT kernel A: xl = h@Wl^T+bl, xr = h@Wr^T+br ---------------
// R8: row-per-lane compute (R7: VGPR=112 no-spill, FETCH sane) + the store
// fix. R7's regression was WRITE amplification (98->477 MB): per-lane
// scattered dword stores dirty partial sectors. Fix: compute 16 cols into
// creg, transpose through a per-wave LDS tile (stride 17, conflict-free;
// same-wave ds ordering needs no barrier), then store row-segments of 64 B
// (full sectors) with 16-lane groups -> 1x write amplification. W rides the
// scalar path (wave-uniform j -> s_load; per-wave W slice 16 KB).
__global__ __launch_bounds__(128) void xlxr_kernel(
    const float* __restrict__ hin,
    const float* __restrict__ Wl, const float* __restrict__ bl,
    const float* __restrict__ Wr, const float* __restrict__ br,
    float* __restrict__ xl, float* __restrict__ xr) {
  __shared__ float lsh[64 * 68];       // 17.4 KB: h staging, then T tiles
  int tid = threadIdx.x;
  int l = tid & 63;
  int w = __builtin_amdgcn_readfirstlane(tid >> 6);   // 0 -> xl, 1 -> xr
  int row0 = blockIdx.x * 64;
  {
    const float4* src4 = (const float4*)(hin + (size_t)row0 * HH);
#pragma unroll
    for (int i = 0; i < 8; ++i) {
      int idx = i * 128 + tid;
      int r = idx >> 4, c = idx & 15;
      *(float4*)&lsh[r * 68 + c * 4] = src4[idx];
    }
  }
  __syncthreads();
  float hreg[HH];
#pragma unroll
  for (int c = 0; c < 16; ++c)
    *(float4*)&hreg[4 * c] = *(const float4*)&lsh[l * 68 + c * 4];
  __syncthreads();                     // lsh dead -> reusable as T tiles

  const float* W  = w ? Wr : Wl;       // uniform pointers
  const float* bv = w ? br : bl;
  float* outp     = w ? xr : xl;
  float* T = lsh + w * (64 * 17);      // per-wave transpose tile (4.35 KB)
#pragma unroll 1
  for (int ch = 0; ch < 4; ++ch) {
    float creg[16];
#pragma unroll
    for (int jj = 0; jj < 16; ++jj) {
      int j = ch * 16 + jj;
      const float* wrow = W + (size_t)j * HH;   // uniform -> s_load
      float a0 = bv[j], a1 = 0.f, a2 = 0.f, a3 = 0.f;
#pragma unroll
      for (int k = 0; k < HH; k += 4) {
        a0 += hreg[k + 0] * wrow[k + 0];
        a1 += hreg[k + 1] * wrow[k + 1];
        a2 += hreg[k + 2] * wrow[k + 2];
        a3 += hreg[k + 3] * wrow[k + 3];
      }
      creg[jj] = (a0 + a1) + (a2 + a3);
    }
    // lane l -> T[l][c]; stride 17 => banks (17l+c)%32 distinct (free)
#pragma unroll
    for (int c = 0; c < 16; ++c) T[l * 17 + c] = creg[c];
    // same-wave write->read: compiler orders via lgkmcnt, no barrier needed
#pragma unroll
    for (int i = 0; i < 16; ++i) {
      int row = 4 * i + (l >> 4);
      int col = l & 15;
      float v = T[row * 17 + col];
      outp[(size_t)(row0 + row) * HH + ch * 16 + col] = v;  // 64 B/row, full sector
    }
  }
}

// ---------------- GAT kernel B: edge logits + softmax + aggregate ------------
__global__ __launch_bounds__(256) void gat_edge_kernel(
    const float* __restrict__ xl_g, const float* __restrict__ xr_g,
    float* __restrict__ hout,
    const int* __restrict__ csr_off, const int* __restrict__ csr_src,
    const int* __restrict__ csr_tgt,
    const float* __restrict__ att, const float* __restrict__ bo) {
  __shared__ float xl_sh[NN * XPAD];   // 33.3 KB
  __shared__ float xr_sh[NN * XPAD];   // 33.3 KB
  __shared__ float p_sh[ET];
  __shared__ int st_sh[ET];
  __shared__ unsigned m_sh[NN];
  int tid = threadIdx.x, lane = tid & 63, wid = tid >> 6;
  int base = blockIdx.x * (NN * HH);

  // stage xl/xr with padded stride
#pragma unroll 1
  for (int i = tid * 4; i < NN * HH; i += 256 * 4) {
    int row = i >> 6, h = i & 63;
    float4 vl = *(const float4*)(xl_g + base + i);
    float4 vr = *(const float4*)(xr_g + base + i);
    float* dl = xl_sh + row * XPAD + h;
    float* dr = xr_sh + row * XPAD + h;
    dl[0] = vl.x; dl[1] = vl.y; dl[2] = vl.z; dl[3] = vl.w;
    dr[0] = vr.x; dr[1] = vr.y; dr[2] = vr.z; dr[3] = vr.w;
  }
  for (int i = tid; i < ET; i += 256)
    st_sh[i] = csr_src[i] | (csr_tgt[i] << 16);
  if (tid < NN) m_sh[tid] = 0u;
  __syncthreads();

  // pass 1: thread-per-edge attention logit + segment max
#pragma unroll 1
  for (int e = tid; e < ET; e += 256) {
    int st = st_sh[e];
    int s = st & 0xffff, tg = st >> 16;
    const float* xlr = xl_sh + s * XPAD;
    const float* xrr = xr_sh + tg * XPAD;
    float a0 = 0.f, a1 = 0.f, a2 = 0.f, a3 = 0.f;
#pragma unroll
    for (int h = 0; h < HH; h += 4) {
      float v0 = xlr[h + 0] + xrr[h + 0]; v0 = (v0 > 0.f) ? v0 : 0.2f * v0;
      float v1 = xlr[h + 1] + xrr[h + 1]; v1 = (v1 > 0.f) ? v1 : 0.2f * v1;
      float v2 = xlr[h + 2] + xrr[h + 2]; v2 = (v2 > 0.f) ? v2 : 0.2f * v2;
      float v3 = xlr[h + 3] + xrr[h + 3]; v3 = (v3 > 0.f) ? v3 : 0.2f * v3;
      a0 += v0 * att[h + 0];
      a1 += v1 * att[h + 1];
      a2 += v2 * att[h + 2];
      a3 += v3 * att[h + 3];
    }
    float a = (a0 + a1) + (a2 + a3);
    p_sh[e] = a;
    atomicMax(&m_sh[tg], flipf(a));
  }
  __syncthreads();

  // pass 2: stabilized exp
  for (int e = tid; e < ET; e += 256) {
    int tg = st_sh[e] >> 16;
    p_sh[e] = expf(p_sh[e] - unflipf(m_sh[tg]));
  }
  __syncthreads();

  // gather: wave per target node, CSR-contiguous edge segment
  float bo_l = bo[lane];
#pragma unroll 1
  for (int n = wid; n < NN; n += 4) {
    int o0 = __builtin_amdgcn_readfirstlane(csr_off[n]);
    int o1 = __builtin_amdgcn_readfirstlane(csr_off[n + 1]);
    float acc = 0.f, z = 0.f;
    for (int i = o0; i < o1; ++i) {
      float p = p_sh[i];
      int s = st_sh[i] & 0xffff;
      acc += p * xl_sh[s * XPAD + lane];
      z += p;
    }
    float o = acc / z + bo_l;
    hout[base + n * HH + lane] = fmaxf(o, 0.f);
  }
}

// ---------------- fallback fused GAT (used if ws too small) ------------------
__device__ __forceinline__ void gemm_half(
    const float* __restrict__ hin, int base,
    const float* __restrict__ W, const float* __restrict__ bvec,
    float* __restrict__ out_sh, int half, int lane) {
  float wreg[HH];
#pragma unroll
  for (int i = 0; i < HH / 4; ++i)
    *(float4*)&wreg[4 * i] = ((const float4*)(W + lane * HH))[i];
  float bias = bvec[lane];
  int n0 = __builtin_amdgcn_readfirstlane(half * 64);
#pragma unroll 1
  for (int nd = 0; nd < 64; ++nd) {
    int node = n0 + nd;
    const float* hrow = hin + base + node * HH;
    float a0 = bias, a1 = 0.f, a2 = 0.f, a3 = 0.f;
#pragma unroll
    for (int f = 0; f < HH; f += 4) {
      a0 += hrow[f + 0] * wreg[f + 0];
      a1 += hrow[f + 1] * wreg[f + 1];
      a2 += hrow[f + 2] * wreg[f + 2];
      a3 += hrow[f + 3] * wreg[f + 3];
    }
    out_sh[node * HH + lane] = (a0 + a1) + (a2 + a3);
  }
}

__global__ __launch_bounds__(256) void gat_fused_kernel(
    const float* __restrict__ hin, float* __restrict__ hout,
    const int* __restrict__ csr_off, const int* __restrict__ csr_src,
    const int* __restrict__ csr_tgt,
    const float* __restrict__ Wl, const float* __restrict__ bl,
    const float* __restrict__ Wr, const float* __restrict__ br,
    const float* __restrict__ att, const float* __restrict__ bo) {
  __shared__ float xl_sh[NN * HH];
  __shared__ float xr_sh[NN * HH];
  __shared__ float p_sh[ET];
  __shared__ int st_sh[ET];
  __shared__ unsigned m_sh[NN];
  int tid = threadIdx.x, lane = tid & 63, wid = tid >> 6;
  int base = blockIdx.x * (NN * HH);

  for (int i = tid; i < ET; i += 256)
    st_sh[i] = csr_src[i] | (csr_tgt[i] << 16);
  if (tid < NN) m_sh[tid] = 0u;

  if (wid < 2) gemm_half(hin, base, Wl, bl, xl_sh, wid & 1, lane);
  else         gemm_half(hin, base, Wr, br, xr_sh, wid & 1, lane);

  float att_l = att[lane];
  float bo_l = bo[lane];
  __syncthreads();

#pragma unroll 1
  for (int e = wid; e < ET; e += 4) {
    int st = st_sh[e];
    int s = st & 0xffff, tg = st >> 16;
    float v = xl_sh[s * HH + lane] + xr_sh[tg * HH + lane];
    v = (v > 0.f) ? v : 0.2f * v;
    float prod = v * att_l;
#pragma unroll
    for (int mm = 32; mm; mm >>= 1) prod += __shfl_xor(prod, mm);
    if (lane == 0) {
      p_sh[e] = prod;
      atomicMax(&m_sh[tg], flipf(prod));
    }
  }
  __syncthreads();

  for (int e = tid; e < ET; e += 256) {
    int tg = st_sh[e] >> 16;
    p_sh[e] = expf(p_sh[e] - unflipf(m_sh[tg]));
  }
  __syncthreads();

#pragma unroll 1
  for (int n = wid; n < NN; n += 4) {
    int o0 = csr_off[n], o1 = csr_off[n + 1];
    float acc = 0.f, z = 0.f;
    for (int i = o0; i < o1; ++i) {
      float p = p_sh[i];
      int s = st_sh[i] & 0xffff;
      acc += p * xl_sh[s * HH + lane];
      z += p;
    }
    float o = acc / z + bo_l;
    hout[base + n * HH + lane] = fmaxf(o, 0.f);
  }
}

// ---------------- GRU stage A: gi = hbuf @ Wih^T + bih  (batched GEMM) -------
// R8: row-per-lane + scalar-path W + LDS-transpose coalesced stores (see
// xlxr comment). 192 threads = 3 gate-waves; wave g covers cols g*64..+64
// (per-wave W slice 16 KB). Lane l holds h row row0+l in 64 VGPRs.
// VGPR ~100 (hreg 64 + creg 16 + addr) < the 128 cliff.
__global__ __launch_bounds__(192) void gi_proj_kernel(
    const float* __restrict__ hin, const float* __restrict__ Wih,
    const float* __restrict__ bih, float* __restrict__ gi) {
  __shared__ float lsh[64 * 68];       // 17.4 KB: h staging, then 3 T tiles
  int tid = threadIdx.x;
  int l = tid & 63;
  int g = __builtin_amdgcn_readfirstlane(tid >> 6);   // gate wave 0..2
  int row0 = blockIdx.x * 64;
  {
    const float4* src4 = (const float4*)(hin + (size_t)row0 * HH);
#pragma unroll 1
    for (int i = tid; i < 1024; i += 192) {
      int r = i >> 4, c = i & 15;
      *(float4*)&lsh[r * 68 + c * 4] = src4[i];
    }
  }
  __syncthreads();
  float hreg[HH];
#pragma unroll
  for (int c = 0; c < 16; ++c)
    *(float4*)&hreg[4 * c] = *(const float4*)&lsh[l * 68 + c * 4];
  __syncthreads();                     // lsh dead -> reusable as T tiles

  float* T = lsh + g * (64 * 17);      // per-wave transpose tile (4.35 KB)
  int j0 = g * 64;
#pragma unroll 1
  for (int ch = 0; ch < 4; ++ch) {
    float creg[16];
#pragma unroll
    for (int jj = 0; jj < 16; ++jj) {
      int j = j0 + ch * 16 + jj;
      const float* wrow = Wih + (size_t)j * HH;   // uniform -> s_load
      float a0 = bih[j], a1 = 0.f, a2 = 0.f, a3 = 0.f;
#pragma unroll
      for (int k = 0; k < HH; k += 4) {
        a0 += hreg[k + 0] * wrow[k + 0];
        a1 += hreg[k + 1] * wrow[k + 1];
        a2 += hreg[k + 2] * wrow[k + 2];
        a3 += hreg[k + 3] * wrow[k + 3];
      }
      creg[jj] = (a0 + a1) + (a2 + a3);
    }
#pragma unroll
    for (int c = 0; c < 16; ++c) T[l * 17 + c] = creg[c];
    // same-wave write->read ordered by lgkmcnt; no barrier needed
#pragma unroll
    for (int i = 0; i < 16; ++i) {
      int row = 4 * i + (l >> 4);
      int col = l & 15;
      float v = T[row * 17 + col];
      gi[(size_t)(row0 + row) * 192 + j0 + ch * 16 + col] = v;  // full sectors
    }
  }
}

// ---------------- GRU stage B: recurrence, one wave per sequence -------------
// R3 configuration (best-evidenced: ~90 us, no spill). 2048 blocks x 64
// threads; zero barriers, zero cross-wave traffic. Lane j holds Whh rows
// {j, 64+j, 128+j} (192 floats). h broadcast = v_readlane of the wave's own
// hj. gi streamed with depth-2 prefetch. 2048 waves chip-resident.
__global__ __launch_bounds__(64, 2) void gru_rec_kernel(
    const float* __restrict__ gi,
    const float* __restrict__ Whh, const float* __restrict__ bhh,
    const float* __restrict__ oW1, const float* __restrict__ ob1,
    const float* __restrict__ oW2, const float* __restrict__ ob2,
    const float* __restrict__ dW1, const float* __restrict__ db1,
    const float* __restrict__ dW2, const float* __restrict__ db2,
    float* __restrict__ out) {
  int lane = threadIdx.x;                      // 0..63
  int seq = blockIdx.x;                        // b*N + n
  int b = seq >> 7, n = seq & (NN - 1);

  float wr[HH], wz[HH], wn[HH];
  {
    const float4* s0 = (const float4*)(Whh + (size_t)(0 * 64 + lane) * HH);
    const float4* s1 = (const float4*)(Whh + (size_t)(1 * 64 + lane) * HH);
    const float4* s2 = (const float4*)(Whh + (size_t)(2 * 64 + lane) * HH);
#pragma unroll
    for (int i = 0; i < HH / 4; ++i) {
      *(float4*)&wr[4 * i] = s0[i];
      *(float4*)&wz[4 * i] = s1[i];
      *(float4*)&wn[4 * i] = s2[i];
    }
  }
  float br_ = bhh[lane], bz_ = bhh[64 + lane], bn_ = bhh[128 + lane];

  const float* gbase = gi + ((size_t)b * SS * NN + (size_t)n) * 192;  // +t*NN*192
  // depth-2 software pipeline on gi loads
  float gir = gbase[lane], giz = gbase[64 + lane], gin = gbase[128 + lane];
  const float* g1 = gbase + (size_t)NN * 192;
  float pir = g1[lane], piz = g1[64 + lane], pin = g1[128 + lane];
  float hj = 0.f;

#pragma unroll 1
  for (int t = 0; t < SS; ++t) {
    float qir = 0.f, qiz = 0.f, qin = 0.f;
    if (t + 2 < SS) {
      const float* g2 = gbase + (size_t)(t + 2) * NN * 192;
      qir = g2[lane]; qiz = g2[64 + lane]; qin = g2[128 + lane];
    }
    float ar0 = br_, ar1 = 0.f, az0 = bz_, az1 = 0.f, an0 = bn_, an1 = 0.f;
#pragma unroll
    for (int k = 0; k < HH; k += 2) {
      float h0 = readlane_f(hj, k), h1 = readlane_f(hj, k + 1);
      ar0 += h0 * wr[k];     az0 += h0 * wz[k];     an0 += h0 * wn[k];
      ar1 += h1 * wr[k + 1]; az1 += h1 * wz[k + 1]; an1 += h1 * wn[k + 1];
    }
    float r  = sigmoidf_(gir + ar0 + ar1);
    float z  = sigmoidf_(giz + az0 + az1);
    float nn_ = tanhf(gin + r * (an0 + an1));
    hj = (1.f - z) * nn_ + z * hj;
    gir = pir; giz = piz; gin = pin;
    pir = qir; piz = qiz; pin = qin;
  }

  // ---- fused heads: lanes 0..31 = order head, 32..63 = demand head ----
  int half = lane >> 5, jp = lane & 31;
  const float* W1 = half ? dW1 : oW1;
  const float* b1 = half ? db1 : ob1;
  const float* W2 = half ? dW2 : oW2;
  const float* b2 = half ? db2 : ob2;
  float wv[HH];
#pragma unroll
  for (int i = 0; i < HH / 4; ++i)
    *(float4*)&wv[4 * i] = ((const float4*)(W1 + jp * HH))[i];
  float acc = b1[jp];
#pragma unroll
  for (int k = 0; k < HH; ++k)
    acc += readlane_f(hj, k) * wv[k];            // broadcast from own h copy
  float val = fmaxf(acc, 0.f) * W2[jp];
  val += __shfl_down(val, 16, 32);
  val += __shfl_down(val, 8, 32);
  val += __shfl_down(val, 4, 32);
  val += __shfl_down(val, 2, 32);
  val += __shfl_down(val, 1, 32);
  if (jp == 0) out[half * (BB * NN) + seq] = val + b2[0];
}

// ---------------- fallback GRU (used if ws too small for gi) -----------------
__global__ __launch_bounds__(192, 3) void gru_fused_kernel(
    const float* __restrict__ hbuf,
    const float* __restrict__ Wih, const float* __restrict__ Whh,
    const float* __restrict__ bih, const float* __restrict__ bhh,
    const float* __restrict__ oW1, const float* __restrict__ ob1,
    const float* __restrict__ oW2, const float* __restrict__ ob2,
    const float* __restrict__ dW1, const float* __restrict__ db1,
    const float* __restrict__ dW2, const float* __restrict__ db2,
    float* __restrict__ out) {
  __shared__ float gi_sh[SS * 3 * HH];   // 48 KB  [t][gate][j]
  __shared__ float exch[2][3][HH];       // double-buffered gh exchange

  int lane = threadIdx.x & 63;
  int g = (int)threadIdx.x >> 6;
  int seq = blockIdx.x;
  int b = seq >> 7, n = seq & (NN - 1);
  const float* xbase = hbuf + ((size_t)b * SS * NN + (size_t)n) * HH;

  {
    float w[HH];
    const float4* wsrc = (const float4*)(Wih + (size_t)(g * 64 + lane) * HH);
#pragma unroll
    for (int i = 0; i < HH / 4; ++i) *(float4*)&w[4 * i] = wsrc[i];
    float bias = bih[g * 64 + lane];
#pragma unroll 2
    for (int t = 0; t < SS; ++t) {
      const float* xr = xbase + (size_t)t * NN * HH;
      float a0 = bias, a1 = 0.f, a2 = 0.f, a3 = 0.f;
#pragma unroll
      for (int k = 0; k < HH; k += 4) {
        float4 xb = *(const float4*)(xr + k);
        a0 += xb.x * w[k + 0];
        a1 += xb.y * w[k + 1];
        a2 += xb.z * w[k + 2];
        a3 += xb.w * w[k + 3];
      }
      gi_sh[(t * 3 + g) * HH + lane] = (a0 + a1) + (a2 + a3);
    }
  }

  float whh[HH];
  {
    const float4* wsrc = (const float4*)(Whh + (size_t)(g * 64 + lane) * HH);
#pragma unroll
    for (int i = 0; i < HH / 4; ++i) *(float4*)&whh[4 * i] = wsrc[i];
  }
  float bhg = bhh[g * 64 + lane];
  float hj = 0.f;
  __syncthreads();

#pragma unroll 1
  for (int t = 0; t < SS; ++t) {
    float a0 = bhg, a1 = 0.f, a2 = 0.f, a3 = 0.f;
#pragma unroll
    for (int k = 0; k < HH; k += 4) {
      a0 += readlane_f(hj, k + 0) * whh[k + 0];
      a1 += readlane_f(hj, k + 1) * whh[k + 1];
      a2 += readlane_f(hj, k + 2) * whh[k + 2];
      a3 += readlane_f(hj, k + 3) * whh[k + 3];
    }
    float gh = (a0 + a1) + (a2 + a3);
    int slot = t & 1;
    exch[slot][g][lane] = gh;
    __syncthreads();
    float ghr = exch[slot][0][lane];
    float ghz = exch[slot][1][lane];
    float ghn = exch[slot][2][lane];
    float gir = gi_sh[(t * 3 + 0) * HH + lane];
    float giz = gi_sh[(t * 3 + 1) * HH + lane];
    float gin = gi_sh[(t * 3 + 2) * HH + lane];
    float r  = sigmoidf_(gir + ghr);
    float z  = sigmoidf_(giz + ghz);
    float nn_ = tanhf(gin + r * ghn);
    hj = (1.f - z) * nn_ + z * hj;
  }

  if (g == 0) {
    int half = lane >> 5, jp = lane & 31;
    const float* W1 = half ? dW1 : oW1;
    const float* b1 = half ? db1 : ob1;
    const float* W2 = half ? dW2 : oW2;
    const float* b2 = half ? db2 : ob2;
    float wv[HH];
#pragma unroll
    for (int i = 0; i < HH / 4; ++i)
      *(float4*)&wv[4 * i] = ((const float4*)(W1 + jp * HH))[i];
    float acc = b1[jp];
#pragma unroll
    for (int k = 0; k < HH; ++k)
      acc += readlane_f(hj, k) * wv[k];
    float val = fmaxf(acc, 0.f) * W2[jp];
    val += __shfl_down(val, 16, 32);
    val += __shfl_down(val, 8, 32);
    val += __shfl_down(val, 4, 32);
    val += __shfl_down(val, 2, 32);
    val += __shfl_down(val, 1, 32);
    if (jp == 0) out[half * (BB * NN) + seq] = val + b2[0];
  }
}

// ---------------- launch -----------------------------------------------------
extern "C" void kernel_launch(void* const* d_in, const int* in_sizes, int n_in,
                              void* d_out, int out_size, void* d_ws, size_t ws_size,
                              hipStream_t stream) {
  const float* x       = (const float*)d_in[0];
  const int*   ei      = (const int*)d_in[1];
  const float* in_W    = (const float*)d_in[2];
  const float* in_b    = (const float*)d_in[3];
  const float* gat_Wl  = (const float*)d_in[4];
  const float* gat_bl  = (const float*)d_in[5];
  const float* gat_Wr  = (const float*)d_in[6];
  const float* gat_br  = (const float*)d_in[7];
  const float* gat_att = (const float*)d_in[8];
  const float* gat_bias= (const float*)d_in[9];
  const float* gru_Wih = (const float*)d_in[10];
  const float* gru_Whh = (const float*)d_in[11];
  const float* gru_bih = (const float*)d_in[12];
  const float* gru_bhh = (const float*)d_in[13];
  const float* oh_W1   = (const float*)d_in[14];
  const float* oh_b1   = (const float*)d_in[15];
  const float* oh_W2   = (const float*)d_in[16];
  const float* oh_b2   = (const float*)d_in[17];
  const float* dh_W1   = (const float*)d_in[18];
  const float* dh_b1   = (const float*)d_in[19];
  const float* dh_W2   = (const float*)d_in[20];
  const float* dh_b2   = (const float*)d_in[21];
  float* out = (float*)d_out;

  char* ws = (char*)d_ws;
  size_t hfloats = (size_t)BB * SS * NN * HH;           // 8.39M floats
  float* hbuf = (float*)ws;
  size_t off_csr = hfloats * sizeof(float);
  size_t off_buf = off_csr + (160 + 2 * ET) * sizeof(int);
  off_buf = (off_buf + 255) & ~(size_t)255;             // 256B align
  int* csr_off = (int*)(ws + off_csr);
  int* csr_src = csr_off + 160;
  int* csr_tgt = csr_src + ET;
  float* xlbuf = (float*)(ws + off_buf);
  float* xrbuf = xlbuf + hfloats;
  size_t need_gat = off_buf + 2 * hfloats * sizeof(float);
  bool big_gat = (ws_size >= need_gat);
  // gi buffer overlays xl/xr (dead after the GAT layers): RT*192 floats
  float* gibuf = (float*)(ws + off_buf);
  size_t need_gru = off_buf + (size_t)RT * 192 * sizeof(float);  // ~134 MB
  bool big_gru = (ws_size >= need_gru);

  setup_csr_kernel<<<1, 256, 0, stream>>>(ei, csr_off, csr_src, csr_tgt);
  input_proj_kernel<<<(BB * SS * NN) / (4 * 32), 256, 0, stream>>>(x, in_W, in_b, hbuf);
  for (int l = 0; l < LLAYERS; ++l) {
    if (big_gat) {
      xlxr_kernel<<<RT / 64, 128, 0, stream>>>(
          hbuf, gat_Wl + l * HH * HH, gat_bl + l * HH,
          gat_Wr + l * HH * HH, gat_br + l * HH, xlbuf, xrbuf);
      gat_edge_kernel<<<BB * SS, 256, 0, stream>>>(
          xlbuf, xrbuf, hbuf, csr_off, csr_src, csr_tgt,
          gat_att + l * HH, gat_bias + l * HH);
    } else {
      gat_fused_kernel<<<BB * SS, 256, 0, stream>>>(
          hbuf, hbuf, csr_off, csr_src, csr_tgt,
          gat_Wl + l * HH * HH, gat_bl + l * HH,
          gat_Wr + l * HH * HH, gat_br + l * HH,
          gat_att + l * HH, gat_bias + l * HH);
    }
  }
  if (big_gru) {
    gi_proj_kernel<<<RT / 64, 192, 0, stream>>>(hbuf, gru_Wih, gru_bih, gibuf);
    gru_rec_kernel<<<BB * NN, 64, 0, stream>>>(
        gibuf, gru_Whh, gru_bhh,
        oh_W1, oh_b1, oh_W2, oh_b2, dh_W1, dh_b1, dh_W2, dh_b2, out);
  } else {
    gru_fused_kernel<<<BB * NN, 192, 0, stream>>>(
        hbuf, gru_Wih, gru_Whh, gru_bih, gru_bhh,
        oh_W1, oh_b1, oh_W2, oh_b2, dh_W1, dh_b1, dh_W2, dh_b2, out);
  }
}

// Round 9
// 683.948 us; speedup vs baseline: 1.6270x; 1.6270x over previous
//
#include <hip/hip_runtime.h>
#include <math.h>

#define BB 16
#define SS 64
#define NN 128
#define FF 16
#define HH 64
#define EE 1024
#define ET 1152   // EE + NN self-loops
#define LLAYERS 2
#define XPAD 65   // padded LDS row stride for gat_edge staging
#define RT (BB * SS * NN)   // 131072 GRU input rows

__device__ __forceinline__ float readlane_f(float v, int k) {
  return __int_as_float(__builtin_amdgcn_readlane(__float_as_int(v), k));
}
// monotonic float<->uint mapping for atomicMax-based float max
__device__ __forceinline__ unsigned flipf(float f) {
  unsigned u = __float_as_uint(f);
  unsigned mask = (u & 0x80000000u) ? 0xFFFFFFFFu : 0x80000000u;
  return u ^ mask;
}
__device__ __forceinline__ float unflipf(unsigned u) {
  unsigned b = (u & 0x80000000u) ? (u ^ 0x80000000u) : ~u;
  return __uint_as_float(b);
}
__device__ __forceinline__ float sigmoidf_(float x) { return 1.f / (1.f + expf(-x)); }

// ---------------- CSR setup (graph is identical for every (b,s)) -------------
__global__ void setup_csr_kernel(const int* __restrict__ ei,
                                 int* __restrict__ off,
                                 int* __restrict__ csrc,
                                 int* __restrict__ ctgt) {
  __shared__ int deg[NN], cur[NN], offs[NN + 1];
  int tid = threadIdx.x;
  if (tid < NN) deg[tid] = 0;
  __syncthreads();
  for (int e = tid; e < ET; e += 256) {
    int tg = (e < EE) ? ei[EE + e] : (e - EE);
    atomicAdd(&deg[tg], 1);
  }
  __syncthreads();
  if (tid == 0) {
    int s = 0;
    for (int i = 0; i < NN; ++i) { offs[i] = s; s += deg[i]; }
    offs[NN] = s;
  }
  __syncthreads();
  if (tid < NN) cur[tid] = offs[tid];
  if (tid <= NN) off[tid] = offs[tid];
  __syncthreads();
  for (int e = tid; e < ET; e += 256) {
    int sv, tg;
    if (e < EE) { sv = ei[e]; tg = ei[EE + e]; }
    else        { sv = e - EE; tg = e - EE; }
    int pos = atomicAdd(&cur[tg], 1);
    csrc[pos] = sv;
    ctgt[pos] = tg;
  }
}

// ---------------- input projection: h = x @ W^T + b --------------------------
__global__ __launch_bounds__(256) void input_proj_kernel(
    const float* __restrict__ x, const float* __restrict__ W,
    const float* __restrict__ bvec, float* __restrict__ h) {
  int lane = threadIdx.x & 63;
  int wid = threadIdx.x >> 6;
  float wreg[FF];
#pragma unroll
  for (int i = 0; i < FF / 4; ++i)
    *(float4*)&wreg[4 * i] = ((const float4*)(W + lane * FF))[i];
  float bias = bvec[lane];
  int row0 = __builtin_amdgcn_readfirstlane((blockIdx.x * 4 + wid) * 32);
#pragma unroll 2
  for (int r = 0; r < 32; ++r) {
    int row = row0 + r;
    const float* xr = x + row * FF;
    float acc = bias;
#pragma unroll
    for (int f = 0; f < FF; ++f) acc += xr[f] * wreg[f];
    h[row * HH + lane] = acc;
  }
}

// ---------------- GAT kernel A: xl = h@Wl^T+bl, xr = h@Wr^T+br ---------------
// R9: readlane-GEMM. Measured walls: R6 uniform-ds_read broadcast = LDS-pipe
// bound (121us gi: each b128 returns 1024B of bandwidth for 16 useful bytes);
// R7 scattered stores = 5x write-amp; R8 = VGPR 132 > 128 occupancy step.
// This design: h broadcast via v_readlane from the wave's OWN registers
// (pure VALU, zero LDS steady-state; primitive proven in R0/R3 gru).
// Register math under the 128 cliff via split-h: lanes 0-31 hold rows 0-31
// k[0,32), lanes 32-63 hold the same rows k[32,64) -> 32 floats/lane;
// h[r][k] = readlane(hreg[k&31], r + (k>=32)*32). wreg 64 + hreg 32 ~ 106
// VGPR -> 4 waves/SIMD. Rows in 2 batches of 32. Stores coalesced 256 B.
__global__ __launch_bounds__(128) void xlxr_kernel(
    const float* __restrict__ hin,
    const float* __restrict__ Wl, const float* __restrict__ bl,
    const float* __restrict__ Wr, const float* __restrict__ br,
    float* __restrict__ xl, float* __restrict__ xr) {
  __shared__ float lsh[64 * 68];       // 17.4 KB staging (one-time)
  int tid = threadIdx.x;
  int j = tid & 63;                    // output column / lane
  int w = tid >> 6;                    // 0 -> xl, 1 -> xr
  int row0 = blockIdx.x * 64;
  {
    const float4* src4 = (const float4*)(hin + (size_t)row0 * HH);
#pragma unroll
    for (int i = 0; i < 8; ++i) {
      int idx = i * 128 + tid;
      int r = idx >> 4, c = idx & 15;
      *(float4*)&lsh[r * 68 + c * 4] = src4[idx];
    }
  }
  const float* W  = w ? Wr : Wl;
  const float* bv = w ? br : bl;
  float* outp     = w ? xr : xl;
  float wreg[HH];
  {
    const float4* ws_ = (const float4*)(W + (size_t)j * HH);
#pragma unroll
    for (int i = 0; i < HH / 4; ++i) *(float4*)&wreg[4 * i] = ws_[i];
  }
  float bias = bv[j];
  int khalf = (j >> 5) * 32;           // which k-half this lane stores
  int rloc = j & 31;                   // which row (within batch) it stores
  __syncthreads();

#pragma unroll 1
  for (int b = 0; b < 2; ++b) {
    float hreg[32];
    {
      const float* hr = &lsh[(b * 32 + rloc) * 68 + khalf];
#pragma unroll
      for (int i = 0; i < 8; ++i)
        *(float4*)&hreg[4 * i] = *(const float4*)&hr[4 * i];
    }
#pragma unroll 1
    for (int r = 0; r < 32; ++r) {
      int r32 = r + 32;
      float a0 = bias, a1 = 0.f, a2 = 0.f, a3 = 0.f;
#pragma unroll
      for (int k = 0; k < 32; k += 4) {
        a0 += readlane_f(hreg[k + 0], r) * wreg[k + 0];
        a1 += readlane_f(hreg[k + 1], r) * wreg[k + 1];
        a2 += readlane_f(hreg[k + 2], r) * wreg[k + 2];
        a3 += readlane_f(hreg[k + 3], r) * wreg[k + 3];
      }
#pragma unroll
      for (int k = 0; k < 32; k += 4) {
        a0 += readlane_f(hreg[k + 0], r32) * wreg[32 + k + 0];
        a1 += readlane_f(hreg[k + 1], r32) * wreg[32 + k + 1];
        a2 += readlane_f(hreg[k + 2], r32) * wreg[32 + k + 2];
        a3 += readlane_f(hreg[k + 3], r32) * wreg[32 + k + 3];
      }
      outp[(size_t)(row0 + b * 32 + r) * HH + j] = (a0 + a1) + (a2 + a3);
    }
  }
}

// ---------------- GAT kernel B: edge logits + softmax + aggregate ------------
__global__ __launch_bounds__(256) void gat_edge_kernel(
    const float* __restrict__ xl_g, const float* __restrict__ xr_g,
    float* __restrict__ hout,
    const int* __restrict__ csr_off, const int* __restrict__ csr_src,
    const int* __restrict__ csr_tgt,
    const float* __restrict__ att, const float* __restrict__ bo) {
  __shared__ float xl_sh[NN * XPAD];   // 33.3 KB
  __shared__ float xr_sh[NN * XPAD];   // 33.3 KB
  __shared__ float p_sh[ET];
  __shared__ int st_sh[ET];
  __shared__ unsigned m_sh[NN];
  int tid = threadIdx.x, lane = tid & 63, wid = tid >> 6;
  int base = blockIdx.x * (NN * HH);

  // stage xl/xr with padded stride
#pragma unroll 1
  for (int i = tid * 4; i < NN * HH; i += 256 * 4) {
    int row = i >> 6, h = i & 63;
    float4 vl = *(const float4*)(xl_g + base + i);
    float4 vr = *(const float4*)(xr_g + base + i);
    float* dl = xl_sh + row * XPAD + h;
    float* dr = xr_sh + row * XPAD + h;
    dl[0] = vl.x; dl[1] = vl.y; dl[2] = vl.z; dl[3] = vl.w;
    dr[0] = vr.x; dr[1] = vr.y; dr[2] = vr.z; dr[3] = vr.w;
  }
  for (int i = tid; i < ET; i += 256)
    st_sh[i] = csr_src[i] | (csr_tgt[i] << 16);
  if (tid < NN) m_sh[tid] = 0u;
  __syncthreads();

  // pass 1: thread-per-edge attention logit + segment max
#pragma unroll 1
  for (int e = tid; e < ET; e += 256) {
    int st = st_sh[e];
    int s = st & 0xffff, tg = st >> 16;
    const float* xlr = xl_sh + s * XPAD;
    const float* xrr = xr_sh + tg * XPAD;
    float a0 = 0.f, a1 = 0.f, a2 = 0.f, a3 = 0.f;
#pragma unroll
    for (int h = 0; h < HH; h += 4) {
      float v0 = xlr[h + 0] + xrr[h + 0]; v0 = (v0 > 0.f) ? v0 : 0.2f * v0;
      float v1 = xlr[h + 1] + xrr[h + 1]; v1 = (v1 > 0.f) ? v1 : 0.2f * v1;
      float v2 = xlr[h + 2] + xrr[h + 2]; v2 = (v2 > 0.f) ? v2 : 0.2f * v2;
      float v3 = xlr[h + 3] + xrr[h + 3]; v3 = (v3 > 0.f) ? v3 : 0.2f * v3;
      a0 += v0 * att[h + 0];
      a1 += v1 * att[h + 1];
      a2 += v2 * att[h + 2];
      a3 += v3 * att[h + 3];
    }
    float a = (a0 + a1) + (a2 + a3);
    p_sh[e] = a;
    atomicMax(&m_sh[tg], flipf(a));
  }
  __syncthreads();

  // pass 2: stabilized exp
  for (int e = tid; e < ET; e += 256) {
    int tg = st_sh[e] >> 16;
    p_sh[e] = expf(p_sh[e] - unflipf(m_sh[tg]));
  }
  __syncthreads();

  // gather: wave per target node, CSR-contiguous edge segment
  float bo_l = bo[lane];
#pragma unroll 1
  for (int n = wid; n < NN; n += 4) {
    int o0 = __builtin_amdgcn_readfirstlane(csr_off[n]);
    int o1 = __builtin_amdgcn_readfirstlane(csr_off[n + 1]);
    float acc = 0.f, z = 0.f;
    for (int i = o0; i < o1; ++i) {
      float p = p_sh[i];
      int s = st_sh[i] & 0xffff;
      acc += p * xl_sh[s * XPAD + lane];
      z += p;
    }
    float o = acc / z + bo_l;
    hout[base + n * HH + lane] = fmaxf(o, 0.f);
  }
}

// ---------------- fallback fused GAT (used if ws too small) ------------------
__device__ __forceinline__ void gemm_half(
    const float* __restrict__ hin, int base,
    const float* __restrict__ W, const float* __restrict__ bvec,
    float* __restrict__ out_sh, int half, int lane) {
  float wreg[HH];
#pragma unroll
  for (int i = 0; i < HH / 4; ++i)
    *(float4*)&wreg[4 * i] = ((const float4*)(W + lane * HH))[i];
  float bias = bvec[lane];
  int n0 = __builtin_amdgcn_readfirstlane(half * 64);
#pragma unroll 1
  for (int nd = 0; nd < 64; ++nd) {
    int node = n0 + nd;
    const float* hrow = hin + base + node * HH;
    float a0 = bias, a1 = 0.f, a2 = 0.f, a3 = 0.f;
#pragma unroll
    for (int f = 0; f < HH; f += 4) {
      a0 += hrow[f + 0] * wreg[f + 0];
      a1 += hrow[f + 1] * wreg[f + 1];
      a2 += hrow[f + 2] * wreg[f + 2];
      a3 += hrow[f + 3] * wreg[f + 3];
    }
    out_sh[node * HH + lane] = (a0 + a1) + (a2 + a3);
  }
}

__global__ __launch_bounds__(256) void gat_fused_kernel(
    const float* __restrict__ hin, float* __restrict__ hout,
    const int* __restrict__ csr_off, const int* __restrict__ csr_src,
    const int* __restrict__ csr_tgt,
    const float* __restrict__ Wl, const float* __restrict__ bl,
    const float* __restrict__ Wr, const float* __restrict__ br,
    const float* __restrict__ att, const float* __restrict__ bo) {
  __shared__ float xl_sh[NN * HH];
  __shared__ float xr_sh[NN * HH];
  __shared__ float p_sh[ET];
  __shared__ int st_sh[ET];
  __shared__ unsigned m_sh[NN];
  int tid = threadIdx.x, lane = tid & 63, wid = tid >> 6;
  int base = blockIdx.x * (NN * HH);

  for (int i = tid; i < ET; i += 256)
    st_sh[i] = csr_src[i] | (csr_tgt[i] << 16);
  if (tid < NN) m_sh[tid] = 0u;

  if (wid < 2) gemm_half(hin, base, Wl, bl, xl_sh, wid & 1, lane);
  else         gemm_half(hin, base, Wr, br, xr_sh, wid & 1, lane);

  float att_l = att[lane];
  float bo_l = bo[lane];
  __syncthreads();

#pragma unroll 1
  for (int e = wid; e < ET; e += 4) {
    int st = st_sh[e];
    int s = st & 0xffff, tg = st >> 16;
    float v = xl_sh[s * HH + lane] + xr_sh[tg * HH + lane];
    v = (v > 0.f) ? v : 0.2f * v;
    float prod = v * att_l;
#pragma unroll
    for (int mm = 32; mm; mm >>= 1) prod += __shfl_xor(prod, mm);
    if (lane == 0) {
      p_sh[e] = prod;
      atomicMax(&m_sh[tg], flipf(prod));
    }
  }
  __syncthreads();

  for (int e = tid; e < ET; e += 256) {
    int tg = st_sh[e] >> 16;
    p_sh[e] = expf(p_sh[e] - unflipf(m_sh[tg]));
  }
  __syncthreads();

#pragma unroll 1
  for (int n = wid; n < NN; n += 4) {
    int o0 = csr_off[n], o1 = csr_off[n + 1];
    float acc = 0.f, z = 0.f;
    for (int i = o0; i < o1; ++i) {
      float p = p_sh[i];
      int s = st_sh[i] & 0xffff;
      acc += p * xl_sh[s * HH + lane];
      z += p;
    }
    float o = acc / z + bo_l;
    hout[base + n * HH + lane] = fmaxf(o, 0.f);
  }
}

// ---------------- GRU stage A: gi = hbuf @ Wih^T + bih  (batched GEMM) -------
// R9: readlane-GEMM (see xlxr comment). 192 threads = 3 gate-waves; wave g
// lane j holds Wih row g*64+j (64 floats) + the split-h 32 floats -> ~106
// VGPR, 4 waves/SIMD. Zero steady-state LDS. Stores coalesced 256 B.
__global__ __launch_bounds__(192) void gi_proj_kernel(
    const float* __restrict__ hin, const float* __restrict__ Wih,
    const float* __restrict__ bih, float* __restrict__ gi) {
  __shared__ float lsh[64 * 68];       // 17.4 KB staging (one-time)
  int tid = threadIdx.x;
  int j = tid & 63;
  int g = tid >> 6;                    // gate wave 0..2
  int row0 = blockIdx.x * 64;
  {
    const float4* src4 = (const float4*)(hin + (size_t)row0 * HH);
#pragma unroll 1
    for (int i = tid; i < 1024; i += 192) {
      int r = i >> 4, c = i & 15;
      *(float4*)&lsh[r * 68 + c * 4] = src4[i];
    }
  }
  float wreg[HH];
  {
    const float4* ws_ = (const float4*)(Wih + (size_t)(g * 64 + j) * HH);
#pragma unroll
    for (int i = 0; i < HH / 4; ++i) *(float4*)&wreg[4 * i] = ws_[i];
  }
  float bias = bih[g * 64 + j];
  int khalf = (j >> 5) * 32;
  int rloc = j & 31;
  __syncthreads();

#pragma unroll 1
  for (int b = 0; b < 2; ++b) {
    float hreg[32];
    {
      const float* hr = &lsh[(b * 32 + rloc) * 68 + khalf];
#pragma unroll
      for (int i = 0; i < 8; ++i)
        *(float4*)&hreg[4 * i] = *(const float4*)&hr[4 * i];
    }
#pragma unroll 1
    for (int r = 0; r < 32; ++r) {
      int r32 = r + 32;
      float a0 = bias, a1 = 0.f, a2 = 0.f, a3 = 0.f;
#pragma unroll
      for (int k = 0; k < 32; k += 4) {
        a0 += readlane_f(hreg[k + 0], r) * wreg[k + 0];
        a1 += readlane_f(hreg[k + 1], r) * wreg[k + 1];
        a2 += readlane_f(hreg[k + 2], r) * wreg[k + 2];
        a3 += readlane_f(hreg[k + 3], r) * wreg[k + 3];
      }
#pragma unroll
      for (int k = 0; k < 32; k += 4) {
        a0 += readlane_f(hreg[k + 0], r32) * wreg[32 + k + 0];
        a1 += readlane_f(hreg[k + 1], r32) * wreg[32 + k + 1];
        a2 += readlane_f(hreg[k + 2], r32) * wreg[32 + k + 2];
        a3 += readlane_f(hreg[k + 3], r32) * wreg[32 + k + 3];
      }
      gi[(size_t)(row0 + b * 32 + r) * 192 + g * 64 + j] = (a0 + a1) + (a2 + a3);
    }
  }
}

// ---------------- GRU stage B: recurrence, one wave per sequence -------------
// R3 configuration (best-evidenced: ~90 us, no spill). 2048 blocks x 64
// threads; zero barriers, zero cross-wave traffic. Lane j holds Whh rows
// {j, 64+j, 128+j} (192 floats). h broadcast = v_readlane of the wave's own
// hj. gi streamed with depth-2 prefetch. 2048 waves chip-resident.
__global__ __launch_bounds__(64, 2) void gru_rec_kernel(
    const float* __restrict__ gi,
    const float* __restrict__ Whh, const float* __restrict__ bhh,
    const float* __restrict__ oW1, const float* __restrict__ ob1,
    const float* __restrict__ oW2, const float* __restrict__ ob2,
    const float* __restrict__ dW1, const float* __restrict__ db1,
    const float* __restrict__ dW2, const float* __restrict__ db2,
    float* __restrict__ out) {
  int lane = threadIdx.x;                      // 0..63
  int seq = blockIdx.x;                        // b*N + n
  int b = seq >> 7, n = seq & (NN - 1);

  float wr[HH], wz[HH], wn[HH];
  {
    const float4* s0 = (const float4*)(Whh + (size_t)(0 * 64 + lane) * HH);
    const float4* s1 = (const float4*)(Whh + (size_t)(1 * 64 + lane) * HH);
    const float4* s2 = (const float4*)(Whh + (size_t)(2 * 64 + lane) * HH);
#pragma unroll
    for (int i = 0; i < HH / 4; ++i) {
      *(float4*)&wr[4 * i] = s0[i];
      *(float4*)&wz[4 * i] = s1[i];
      *(float4*)&wn[4 * i] = s2[i];
    }
  }
  float br_ = bhh[lane], bz_ = bhh[64 + lane], bn_ = bhh[128 + lane];

  const float* gbase = gi + ((size_t)b * SS * NN + (size_t)n) * 192;  // +t*NN*192
  // depth-2 software pipeline on gi loads
  float gir = gbase[lane], giz = gbase[64 + lane], gin = gbase[128 + lane];
  const float* g1 = gbase + (size_t)NN * 192;
  float pir = g1[lane], piz = g1[64 + lane], pin = g1[128 + lane];
  float hj = 0.f;

#pragma unroll 1
  for (int t = 0; t < SS; ++t) {
    float qir = 0.f, qiz = 0.f, qin = 0.f;
    if (t + 2 < SS) {
      const float* g2 = gbase + (size_t)(t + 2) * NN * 192;
      qir = g2[lane]; qiz = g2[64 + lane]; qin = g2[128 + lane];
    }
    float ar0 = br_, ar1 = 0.f, az0 = bz_, az1 = 0.f, an0 = bn_, an1 = 0.f;
#pragma unroll
    for (int k = 0; k < HH; k += 2) {
      float h0 = readlane_f(hj, k), h1 = readlane_f(hj, k + 1);
      ar0 += h0 * wr[k];     az0 += h0 * wz[k];     an0 += h0 * wn[k];
      ar1 += h1 * wr[k + 1]; az1 += h1 * wz[k + 1]; an1 += h1 * wn[k + 1];
    }
    float r  = sigmoidf_(gir + ar0 + ar1);
    float z  = sigmoidf_(giz + az0 + az1);
    float nn_ = tanhf(gin + r * (an0 + an1));
    hj = (1.f - z) * nn_ + z * hj;
    gir = pir; giz = piz; gin = pin;
    pir = qir; piz = qiz; pin = qin;
  }

  // ---- fused heads: lanes 0..31 = order head, 32..63 = demand head ----
  int half = lane >> 5, jp = lane & 31;
  const float* W1 = half ? dW1 : oW1;
  const float* b1 = half ? db1 : ob1;
  const float* W2 = half ? dW2 : oW2;
  const float* b2 = half ? db2 : ob2;
  float wv[HH];
#pragma unroll
  for (int i = 0; i < HH / 4; ++i)
    *(float4*)&wv[4 * i] = ((const float4*)(W1 + jp * HH))[i];
  float acc = b1[jp];
#pragma unroll
  for (int k = 0; k < HH; ++k)
    acc += readlane_f(hj, k) * wv[k];            // broadcast from own h copy
  float val = fmaxf(acc, 0.f) * W2[jp];
  val += __shfl_down(val, 16, 32);
  val += __shfl_down(val, 8, 32);
  val += __shfl_down(val, 4, 32);
  val += __shfl_down(val, 2, 32);
  val += __shfl_down(val, 1, 32);
  if (jp == 0) out[half * (BB * NN) + seq] = val + b2[0];
}

// ---------------- fallback GRU (used if ws too small for gi) -----------------
__global__ __launch_bounds__(192, 3) void gru_fused_kernel(
    const float* __restrict__ hbuf,
    const float* __restrict__ Wih, const float* __restrict__ Whh,
    const float* __restrict__ bih, const float* __restrict__ bhh,
    const float* __restrict__ oW1, const float* __restrict__ ob1,
    const float* __restrict__ oW2, const float* __restrict__ ob2,
    const float* __restrict__ dW1, const float* __restrict__ db1,
    const float* __restrict__ dW2, const float* __restrict__ db2,
    float* __restrict__ out) {
  __shared__ float gi_sh[SS * 3 * HH];   // 48 KB  [t][gate][j]
  __shared__ float exch[2][3][HH];       // double-buffered gh exchange

  int lane = threadIdx.x & 63;
  int g = (int)threadIdx.x >> 6;
  int seq = blockIdx.x;
  int b = seq >> 7, n = seq & (NN - 1);
  const float* xbase = hbuf + ((size_t)b * SS * NN + (size_t)n) * HH;

  {
    float w[HH];
    const float4* wsrc = (const float4*)(Wih + (size_t)(g * 64 + lane) * HH);
#pragma unroll
    for (int i = 0; i < HH / 4; ++i) *(float4*)&w[4 * i] = wsrc[i];
    float bias = bih[g * 64 + lane];
#pragma unroll 2
    for (int t = 0; t < SS; ++t) {
      const float* xr = xbase + (size_t)t * NN * HH;
      float a0 = bias, a1 = 0.f, a2 = 0.f, a3 = 0.f;
#pragma unroll
      for (int k = 0; k < HH; k += 4) {
        float4 xb = *(const float4*)(xr + k);
        a0 += xb.x * w[k + 0];
        a1 += xb.y * w[k + 1];
        a2 += xb.z * w[k + 2];
        a3 += xb.w * w[k + 3];
      }
      gi_sh[(t * 3 + g) * HH + lane] = (a0 + a1) + (a2 + a3);
    }
  }

  float whh[HH];
  {
    const float4* wsrc = (const float4*)(Whh + (size_t)(g * 64 + lane) * HH);
#pragma unroll
    for (int i = 0; i < HH / 4; ++i) *(float4*)&whh[4 * i] = wsrc[i];
  }
  float bhg = bhh[g * 64 + lane];
  float hj = 0.f;
  __syncthreads();

#pragma unroll 1
  for (int t = 0; t < SS; ++t) {
    float a0 = bhg, a1 = 0.f, a2 = 0.f, a3 = 0.f;
#pragma unroll
    for (int k = 0; k < HH; k += 4) {
      a0 += readlane_f(hj, k + 0) * whh[k + 0];
      a1 += readlane_f(hj, k + 1) * whh[k + 1];
      a2 += readlane_f(hj, k + 2) * whh[k + 2];
      a3 += readlane_f(hj, k + 3) * whh[k + 3];
    }
    float gh = (a0 + a1) + (a2 + a3);
    int slot = t & 1;
    exch[slot][g][lane] = gh;
    __syncthreads();
    float ghr = exch[slot][0][lane];
    float ghz = exch[slot][1][lane];
    float ghn = exch[slot][2][lane];
    float gir = gi_sh[(t * 3 + 0) * HH + lane];
    float giz = gi_sh[(t * 3 + 1) * HH + lane];
    float gin = gi_sh[(t * 3 + 2) * HH + lane];
    float r  = sigmoidf_(gir + ghr);
    float z  = sigmoidf_(giz + ghz);
    float nn_ = tanhf(gin + r * ghn);
    hj = (1.f - z) * nn_ + z * hj;
  }

  if (g == 0) {
    int half = lane >> 5, jp = lane & 31;
    const float* W1 = half ? dW1 : oW1;
    const float* b1 = half ? db1 : ob1;
    const float* W2 = half ? dW2 : oW2;
    const float* b2 = half ? db2 : ob2;
    float wv[HH];
#pragma unroll
    for (int i = 0; i < HH / 4; ++i)
      *(float4*)&wv[4 * i] = ((const float4*)(W1 + jp * HH))[i];
    float acc = b1[jp];
#pragma unroll
    for (int k = 0; k < HH; ++k)
      acc += readlane_f(hj, k) * wv[k];
    float val = fmaxf(acc, 0.f) * W2[jp];
    val += __shfl_down(val, 16, 32);
    val += __shfl_down(val, 8, 32);
    val += __shfl_down(val, 4, 32);
    val += __shfl_down(val, 2, 32);
    val += __shfl_down(val, 1, 32);
    if (jp == 0) out[half * (BB * NN) + seq] = val + b2[0];
  }
}

// ---------------- launch -----------------------------------------------------
extern "C" void kernel_launch(void* const* d_in, const int* in_sizes, int n_in,
                              void* d_out, int out_size, void* d_ws, size_t ws_size,
                              hipStream_t stream) {
  const float* x       = (const float*)d_in[0];
  const int*   ei      = (const int*)d_in[1];
  const float* in_W    = (const float*)d_in[2];
  const float* in_b    = (const float*)d_in[3];
  const float* gat_Wl  = (const float*)d_in[4];
  const float* gat_bl  = (const float*)d_in[5];
  const float* gat_Wr  = (const float*)d_in[6];
  const float* gat_br  = (const float*)d_in[7];
  const float* gat_att = (const float*)d_in[8];
  const float* gat_bias= (const float*)d_in[9];
  const float* gru_Wih = (const float*)d_in[10];
  const float* gru_Whh = (const float*)d_in[11];
  const float* gru_bih = (const float*)d_in[12];
  const float* gru_bhh = (const float*)d_in[13];
  const float* oh_W1   = (const float*)d_in[14];
  const float* oh_b1   = (const float*)d_in[15];
  const float* oh_W2   = (const float*)d_in[16];
  const float* oh_b2   = (const float*)d_in[17];
  const float* dh_W1   = (const float*)d_in[18];
  const float* dh_b1   = (const float*)d_in[19];
  const float* dh_W2   = (const float*)d_in[20];
  const float* dh_b2   = (const float*)d_in[21];
  float* out = (float*)d_out;

  char* ws = (char*)d_ws;
  size_t hfloats = (size_t)BB * SS * NN * HH;           // 8.39M floats
  float* hbuf = (float*)ws;
  size_t off_csr = hfloats * sizeof(float);
  size_t off_buf = off_csr + (160 + 2 * ET) * sizeof(int);
  off_buf = (off_buf + 255) & ~(size_t)255;             // 256B align
  int* csr_off = (int*)(ws + off_csr);
  int* csr_src = csr_off + 160;
  int* csr_tgt = csr_src + ET;
  float* xlbuf = (float*)(ws + off_buf);
  float* xrbuf = xlbuf + hfloats;
  size_t need_gat = off_buf + 2 * hfloats * sizeof(float);
  bool big_gat = (ws_size >= need_gat);
  // gi buffer overlays xl/xr (dead after the GAT layers): RT*192 floats
  float* gibuf = (float*)(ws + off_buf);
  size_t need_gru = off_buf + (size_t)RT * 192 * sizeof(float);  // ~134 MB
  bool big_gru = (ws_size >= need_gru);

  setup_csr_kernel<<<1, 256, 0, stream>>>(ei, csr_off, csr_src, csr_tgt);
  input_proj_kernel<<<(BB * SS * NN) / (4 * 32), 256, 0, stream>>>(x, in_W, in_b, hbuf);
  for (int l = 0; l < LLAYERS; ++l) {
    if (big_gat) {
      xlxr_kernel<<<RT / 64, 128, 0, stream>>>(
          hbuf, gat_Wl + l * HH * HH, gat_bl + l * HH,
          gat_Wr + l * HH * HH, gat_br + l * HH, xlbuf, xrbuf);
      gat_edge_kernel<<<BB * SS, 256, 0, stream>>>(
          xlbuf, xrbuf, hbuf, csr_off, csr_src, csr_tgt,
          gat_att + l * HH, gat_bias + l * HH);
    } else {
      gat_fused_kernel<<<BB * SS, 256, 0, stream>>>(
          hbuf, hbuf, csr_off, csr_src, csr_tgt,
          gat_Wl + l * HH * HH, gat_bl + l * HH,
          gat_Wr + l * HH * HH, gat_br + l * HH,
          gat_att + l * HH, gat_bias + l * HH);
    }
  }
  if (big_gru) {
    gi_proj_kernel<<<RT / 64, 192, 0, stream>>>(hbuf, gru_Wih, gru_bih, gibuf);
    gru_rec_kernel<<<BB * NN, 64, 0, stream>>>(
        gibuf, gru_Whh, gru_bhh,
        oh_W1, oh_b1, oh_W2, oh_b2, dh_W1, dh_b1, dh_W2, dh_b2, out);
  } else {
    gru_fused_kernel<<<BB * NN, 192, 0, stream>>>(
        hbuf, gru_Wih, gru_Whh, gru_bih, gru_bhh,
        oh_W1, oh_b1, oh_W2, oh_b2, dh_W1, dh_b1, dh_W2, dh_b2, out);
  }
}

// Round 10
// 632.115 us; speedup vs baseline: 1.7604x; 1.0820x over previous
//
#include <hip/hip_runtime.h>
#include <math.h>

#define BB 16
#define SS 64
#define NN 128
#define FF 16
#define HH 64
#define EE 1024
#define ET 1152   // EE + NN self-loops
#define LLAYERS 2
#define XPAD 65   // padded LDS row stride for gat_edge staging
#define RT (BB * SS * NN)   // 131072 GRU input rows

__device__ __forceinline__ float readlane_f(float v, int k) {
  return __int_as_float(__builtin_amdgcn_readlane(__float_as_int(v), k));
}
// monotonic float<->uint mapping for atomicMax-based float max
__device__ __forceinline__ unsigned flipf(float f) {
  unsigned u = __float_as_uint(f);
  unsigned mask = (u & 0x80000000u) ? 0xFFFFFFFFu : 0x80000000u;
  return u ^ mask;
}
__device__ __forceinline__ float unflipf(unsigned u) {
  unsigned b = (u & 0x80000000u) ? (u ^ 0x80000000u) : ~u;
  return __uint_as_float(b);
}
__device__ __forceinline__ float sigmoidf_(float x) { return 1.f / (1.f + expf(-x)); }

// ---------------- CSR setup (graph is identical for every (b,s)) -------------
__global__ void setup_csr_kernel(const int* __restrict__ ei,
                                 int* __restrict__ off,
                                 int* __restrict__ csrc,
                                 int* __restrict__ ctgt) {
  __shared__ int deg[NN], cur[NN], offs[NN + 1];
  int tid = threadIdx.x;
  if (tid < NN) deg[tid] = 0;
  __syncthreads();
  for (int e = tid; e < ET; e += 256) {
    int tg = (e < EE) ? ei[EE + e] : (e - EE);
    atomicAdd(&deg[tg], 1);
  }
  __syncthreads();
  if (tid == 0) {
    int s = 0;
    for (int i = 0; i < NN; ++i) { offs[i] = s; s += deg[i]; }
    offs[NN] = s;
  }
  __syncthreads();
  if (tid < NN) cur[tid] = offs[tid];
  if (tid <= NN) off[tid] = offs[tid];
  __syncthreads();
  for (int e = tid; e < ET; e += 256) {
    int sv, tg;
    if (e < EE) { sv = ei[e]; tg = ei[EE + e]; }
    else        { sv = e - EE; tg = e - EE; }
    int pos = atomicAdd(&cur[tg], 1);
    csrc[pos] = sv;
    ctgt[pos] = tg;
  }
}

// ---------------- input projection: h = x @ W^T + b --------------------------
__global__ __launch_bounds__(256) void input_proj_kernel(
    const float* __restrict__ x, const float* __restrict__ W,
    const float* __restrict__ bvec, float* __restrict__ h) {
  int lane = threadIdx.x & 63;
  int wid = threadIdx.x >> 6;
  float wreg[FF];
#pragma unroll
  for (int i = 0; i < FF / 4; ++i)
    *(float4*)&wreg[4 * i] = ((const float4*)(W + lane * FF))[i];
  float bias = bvec[lane];
  int row0 = __builtin_amdgcn_readfirstlane((blockIdx.x * 4 + wid) * 32);
#pragma unroll 2
  for (int r = 0; r < 32; ++r) {
    int row = row0 + r;
    const float* xr = x + row * FF;
    float acc = bias;
#pragma unroll
    for (int f = 0; f < FF; ++f) acc += xr[f] * wreg[f];
    h[row * HH + lane] = acc;
  }
}

// ---------------- GAT kernel A: xl = h@Wl^T+bl, xr = h@Wr^T+br ---------------
// R10: HYBRID operand delivery. Calibrated pipe costs per wave per row:
//   uniform ds_read_b128 x16 = 192 cyc on the per-CU DS pipe (R6: 121us
//   gi matched 24 waves*1024*12cyc exactly -> DS-bound, VALU idle)
//   readlane x64 = ~320 cyc on the per-SIMD VALU pipe (R9: 144us at
//   VALUBusy 72% -> ~5cyc/readlane effective)
// Split k across BOTH pipes so they run concurrently: k[0,32) via uniform
// b128 from LDS (DS), k[32,64) via readlane from split-h registers (VALU).
// hreg: every lane holds row (l&31)'s k-hi 32 floats (lanes l, l+32
// duplicate -> broadcast load, free); h[r][32+q] = readlane(hreg[q], r).
// VGPR ~ wreg64 + hreg32 + temps ~ 110 < 128 occupancy step.
__global__ __launch_bounds__(128) void xlxr_kernel(
    const float* __restrict__ hin,
    const float* __restrict__ Wl, const float* __restrict__ bl,
    const float* __restrict__ Wr, const float* __restrict__ br,
    float* __restrict__ xl, float* __restrict__ xr) {
  __shared__ float lsh[64 * 68];       // 17.4 KB staging (live throughout)
  int tid = threadIdx.x;
  int j = tid & 63;                    // output column / lane
  int w = tid >> 6;                    // 0 -> xl, 1 -> xr
  int row0 = blockIdx.x * 64;
  {
    const float4* src4 = (const float4*)(hin + (size_t)row0 * HH);
#pragma unroll
    for (int i = 0; i < 8; ++i) {
      int idx = i * 128 + tid;
      int r = idx >> 4, c = idx & 15;
      *(float4*)&lsh[r * 68 + c * 4] = src4[idx];
    }
  }
  const float* W  = w ? Wr : Wl;
  const float* bv = w ? br : bl;
  float* outp     = w ? xr : xl;
  float wreg[HH];
  {
    const float4* ws_ = (const float4*)(W + (size_t)j * HH);
#pragma unroll
    for (int i = 0; i < HH / 4; ++i) *(float4*)&wreg[4 * i] = ws_[i];
  }
  float bias = bv[j];
  int rloc = j & 31;                   // row (within batch) this lane caches
  __syncthreads();

#pragma unroll 1
  for (int b = 0; b < 2; ++b) {
    float hreg[32];                    // row rloc of batch b, k in [32,64)
    {
      const float* hr = &lsh[(b * 32 + rloc) * 68 + 32];
#pragma unroll
      for (int i = 0; i < 8; ++i)
        *(float4*)&hreg[4 * i] = *(const float4*)&hr[4 * i];
    }
#pragma unroll 1
    for (int r = 0; r < 32; ++r) {
      const float* hrow = &lsh[(b * 32 + r) * 68];
      float a0 = bias, a1 = 0.f, a2 = 0.f, a3 = 0.f;
      // k-lo via uniform DS broadcast (DS pipe)
#pragma unroll
      for (int k = 0; k < 32; k += 4) {
        float4 hb = *(const float4*)&hrow[k];
        a0 += hb.x * wreg[k + 0];
        a1 += hb.y * wreg[k + 1];
        a2 += hb.z * wreg[k + 2];
        a3 += hb.w * wreg[k + 3];
      }
      // k-hi via readlane (VALU pipe)
#pragma unroll
      for (int q = 0; q < 32; q += 4) {
        a0 += readlane_f(hreg[q + 0], r) * wreg[32 + q + 0];
        a1 += readlane_f(hreg[q + 1], r) * wreg[32 + q + 1];
        a2 += readlane_f(hreg[q + 2], r) * wreg[32 + q + 2];
        a3 += readlane_f(hreg[q + 3], r) * wreg[32 + q + 3];
      }
      outp[(size_t)(row0 + b * 32 + r) * HH + j] = (a0 + a1) + (a2 + a3);
    }
  }
}

// ---------------- GAT kernel B: edge logits + softmax + aggregate ------------
__global__ __launch_bounds__(256) void gat_edge_kernel(
    const float* __restrict__ xl_g, const float* __restrict__ xr_g,
    float* __restrict__ hout,
    const int* __restrict__ csr_off, const int* __restrict__ csr_src,
    const int* __restrict__ csr_tgt,
    const float* __restrict__ att, const float* __restrict__ bo) {
  __shared__ float xl_sh[NN * XPAD];   // 33.3 KB
  __shared__ float xr_sh[NN * XPAD];   // 33.3 KB
  __shared__ float p_sh[ET];
  __shared__ int st_sh[ET];
  __shared__ unsigned m_sh[NN];
  int tid = threadIdx.x, lane = tid & 63, wid = tid >> 6;
  int base = blockIdx.x * (NN * HH);

  // stage xl/xr with padded stride
#pragma unroll 1
  for (int i = tid * 4; i < NN * HH; i += 256 * 4) {
    int row = i >> 6, h = i & 63;
    float4 vl = *(const float4*)(xl_g + base + i);
    float4 vr = *(const float4*)(xr_g + base + i);
    float* dl = xl_sh + row * XPAD + h;
    float* dr = xr_sh + row * XPAD + h;
    dl[0] = vl.x; dl[1] = vl.y; dl[2] = vl.z; dl[3] = vl.w;
    dr[0] = vr.x; dr[1] = vr.y; dr[2] = vr.z; dr[3] = vr.w;
  }
  for (int i = tid; i < ET; i += 256)
    st_sh[i] = csr_src[i] | (csr_tgt[i] << 16);
  if (tid < NN) m_sh[tid] = 0u;
  __syncthreads();

  // pass 1: thread-per-edge attention logit + segment max
#pragma unroll 1
  for (int e = tid; e < ET; e += 256) {
    int st = st_sh[e];
    int s = st & 0xffff, tg = st >> 16;
    const float* xlr = xl_sh + s * XPAD;
    const float* xrr = xr_sh + tg * XPAD;
    float a0 = 0.f, a1 = 0.f, a2 = 0.f, a3 = 0.f;
#pragma unroll
    for (int h = 0; h < HH; h += 4) {
      float v0 = xlr[h + 0] + xrr[h + 0]; v0 = (v0 > 0.f) ? v0 : 0.2f * v0;
      float v1 = xlr[h + 1] + xrr[h + 1]; v1 = (v1 > 0.f) ? v1 : 0.2f * v1;
      float v2 = xlr[h + 2] + xrr[h + 2]; v2 = (v2 > 0.f) ? v2 : 0.2f * v2;
      float v3 = xlr[h + 3] + xrr[h + 3]; v3 = (v3 > 0.f) ? v3 : 0.2f * v3;
      a0 += v0 * att[h + 0];
      a1 += v1 * att[h + 1];
      a2 += v2 * att[h + 2];
      a3 += v3 * att[h + 3];
    }
    float a = (a0 + a1) + (a2 + a3);
    p_sh[e] = a;
    atomicMax(&m_sh[tg], flipf(a));
  }
  __syncthreads();

  // pass 2: stabilized exp
  for (int e = tid; e < ET; e += 256) {
    int tg = st_sh[e] >> 16;
    p_sh[e] = expf(p_sh[e] - unflipf(m_sh[tg]));
  }
  __syncthreads();

  // gather: wave per target node, CSR-contiguous edge segment
  float bo_l = bo[lane];
#pragma unroll 1
  for (int n = wid; n < NN; n += 4) {
    int o0 = __builtin_amdgcn_readfirstlane(csr_off[n]);
    int o1 = __builtin_amdgcn_readfirstlane(csr_off[n + 1]);
    float acc = 0.f, z = 0.f;
    for (int i = o0; i < o1; ++i) {
      float p = p_sh[i];
      int s = st_sh[i] & 0xffff;
      acc += p * xl_sh[s * XPAD + lane];
      z += p;
    }
    float o = acc / z + bo_l;
    hout[base + n * HH + lane] = fmaxf(o, 0.f);
  }
}

// ---------------- fallback fused GAT (used if ws too small) ------------------
__device__ __forceinline__ void gemm_half(
    const float* __restrict__ hin, int base,
    const float* __restrict__ W, const float* __restrict__ bvec,
    float* __restrict__ out_sh, int half, int lane) {
  float wreg[HH];
#pragma unroll
  for (int i = 0; i < HH / 4; ++i)
    *(float4*)&wreg[4 * i] = ((const float4*)(W + lane * HH))[i];
  float bias = bvec[lane];
  int n0 = __builtin_amdgcn_readfirstlane(half * 64);
#pragma unroll 1
  for (int nd = 0; nd < 64; ++nd) {
    int node = n0 + nd;
    const float* hrow = hin + base + node * HH;
    float a0 = bias, a1 = 0.f, a2 = 0.f, a3 = 0.f;
#pragma unroll
    for (int f = 0; f < HH; f += 4) {
      a0 += hrow[f + 0] * wreg[f + 0];
      a1 += hrow[f + 1] * wreg[f + 1];
      a2 += hrow[f + 2] * wreg[f + 2];
      a3 += hrow[f + 3] * wreg[f + 3];
    }
    out_sh[node * HH + lane] = (a0 + a1) + (a2 + a3);
  }
}

__global__ __launch_bounds__(256) void gat_fused_kernel(
    const float* __restrict__ hin, float* __restrict__ hout,
    const int* __restrict__ csr_off, const int* __restrict__ csr_src,
    const int* __restrict__ csr_tgt,
    const float* __restrict__ Wl, const float* __restrict__ bl,
    const float* __restrict__ Wr, const float* __restrict__ br,
    const float* __restrict__ att, const float* __restrict__ bo) {
  __shared__ float xl_sh[NN * HH];
  __shared__ float xr_sh[NN * HH];
  __shared__ float p_sh[ET];
  __shared__ int st_sh[ET];
  __shared__ unsigned m_sh[NN];
  int tid = threadIdx.x, lane = tid & 63, wid = tid >> 6;
  int base = blockIdx.x * (NN * HH);

  for (int i = tid; i < ET; i += 256)
    st_sh[i] = csr_src[i] | (csr_tgt[i] << 16);
  if (tid < NN) m_sh[tid] = 0u;

  if (wid < 2) gemm_half(hin, base, Wl, bl, xl_sh, wid & 1, lane);
  else         gemm_half(hin, base, Wr, br, xr_sh, wid & 1, lane);

  float att_l = att[lane];
  float bo_l = bo[lane];
  __syncthreads();

#pragma unroll 1
  for (int e = wid; e < ET; e += 4) {
    int st = st_sh[e];
    int s = st & 0xffff, tg = st >> 16;
    float v = xl_sh[s * HH + lane] + xr_sh[tg * HH + lane];
    v = (v > 0.f) ? v : 0.2f * v;
    float prod = v * att_l;
#pragma unroll
    for (int mm = 32; mm; mm >>= 1) prod += __shfl_xor(prod, mm);
    if (lane == 0) {
      p_sh[e] = prod;
      atomicMax(&m_sh[tg], flipf(prod));
    }
  }
  __syncthreads();

  for (int e = tid; e < ET; e += 256) {
    int tg = st_sh[e] >> 16;
    p_sh[e] = expf(p_sh[e] - unflipf(m_sh[tg]));
  }
  __syncthreads();

#pragma unroll 1
  for (int n = wid; n < NN; n += 4) {
    int o0 = csr_off[n], o1 = csr_off[n + 1];
    float acc = 0.f, z = 0.f;
    for (int i = o0; i < o1; ++i) {
      float p = p_sh[i];
      int s = st_sh[i] & 0xffff;
      acc += p * xl_sh[s * HH + lane];
      z += p;
    }
    float o = acc / z + bo_l;
    hout[base + n * HH + lane] = fmaxf(o, 0.f);
  }
}

// ---------------- GRU stage A: gi = hbuf @ Wih^T + bih  (batched GEMM) -------
// R10: hybrid operand delivery (see xlxr comment). 192 threads = 3 gate-
// waves; wave g lane j owns output col g*64+j: wreg 64 floats + hreg 32
// (row (j&31) k-hi). k-lo rides the DS pipe (uniform b128 broadcast from
// lsh), k-hi the VALU pipe (readlane). DS/CU ~61us and VALU/SIMD ~48us run
// concurrently vs R6's 121 (DS-saturated) and R9's 144 (VALU-saturated).
__global__ __launch_bounds__(192) void gi_proj_kernel(
    const float* __restrict__ hin, const float* __restrict__ Wih,
    const float* __restrict__ bih, float* __restrict__ gi) {
  __shared__ float lsh[64 * 68];       // 17.4 KB staging (live throughout)
  int tid = threadIdx.x;
  int j = tid & 63;
  int g = tid >> 6;                    // gate wave 0..2
  int row0 = blockIdx.x * 64;
  {
    const float4* src4 = (const float4*)(hin + (size_t)row0 * HH);
#pragma unroll 1
    for (int i = tid; i < 1024; i += 192) {
      int r = i >> 4, c = i & 15;
      *(float4*)&lsh[r * 68 + c * 4] = src4[i];
    }
  }
  float wreg[HH];
  {
    const float4* ws_ = (const float4*)(Wih + (size_t)(g * 64 + j) * HH);
#pragma unroll
    for (int i = 0; i < HH / 4; ++i) *(float4*)&wreg[4 * i] = ws_[i];
  }
  float bias = bih[g * 64 + j];
  int rloc = j & 31;
  __syncthreads();

#pragma unroll 1
  for (int b = 0; b < 2; ++b) {
    float hreg[32];                    // row rloc of batch b, k in [32,64)
    {
      const float* hr = &lsh[(b * 32 + rloc) * 68 + 32];
#pragma unroll
      for (int i = 0; i < 8; ++i)
        *(float4*)&hreg[4 * i] = *(const float4*)&hr[4 * i];
    }
#pragma unroll 1
    for (int r = 0; r < 32; ++r) {
      const float* hrow = &lsh[(b * 32 + r) * 68];
      float a0 = bias, a1 = 0.f, a2 = 0.f, a3 = 0.f;
      // k-lo via uniform DS broadcast (DS pipe)
#pragma unroll
      for (int k = 0; k < 32; k += 4) {
        float4 hb = *(const float4*)&hrow[k];
        a0 += hb.x * wreg[k + 0];
        a1 += hb.y * wreg[k + 1];
        a2 += hb.z * wreg[k + 2];
        a3 += hb.w * wreg[k + 3];
      }
      // k-hi via readlane (VALU pipe)
#pragma unroll
      for (int q = 0; q < 32; q += 4) {
        a0 += readlane_f(hreg[q + 0], r) * wreg[32 + q + 0];
        a1 += readlane_f(hreg[q + 1], r) * wreg[32 + q + 1];
        a2 += readlane_f(hreg[q + 2], r) * wreg[32 + q + 2];
        a3 += readlane_f(hreg[q + 3], r) * wreg[32 + q + 3];
      }
      gi[(size_t)(row0 + b * 32 + r) * 192 + g * 64 + j] = (a0 + a1) + (a2 + a3);
    }
  }
}

// ---------------- GRU stage B: recurrence, one wave per sequence -------------
// R3 configuration (best-evidenced: ~90 us, no spill). 2048 blocks x 64
// threads; zero barriers, zero cross-wave traffic. Lane j holds Whh rows
// {j, 64+j, 128+j} (192 floats). h broadcast = v_readlane of the wave's own
// hj. gi streamed with depth-2 prefetch. 2048 waves chip-resident.
__global__ __launch_bounds__(64, 2) void gru_rec_kernel(
    const float* __restrict__ gi,
    const float* __restrict__ Whh, const float* __restrict__ bhh,
    const float* __restrict__ oW1, const float* __restrict__ ob1,
    const float* __restrict__ oW2, const float* __restrict__ ob2,
    const float* __restrict__ dW1, const float* __restrict__ db1,
    const float* __restrict__ dW2, const float* __restrict__ db2,
    float* __restrict__ out) {
  int lane = threadIdx.x;                      // 0..63
  int seq = blockIdx.x;                        // b*N + n
  int b = seq >> 7, n = seq & (NN - 1);

  float wr[HH], wz[HH], wn[HH];
  {
    const float4* s0 = (const float4*)(Whh + (size_t)(0 * 64 + lane) * HH);
    const float4* s1 = (const float4*)(Whh + (size_t)(1 * 64 + lane) * HH);
    const float4* s2 = (const float4*)(Whh + (size_t)(2 * 64 + lane) * HH);
#pragma unroll
    for (int i = 0; i < HH / 4; ++i) {
      *(float4*)&wr[4 * i] = s0[i];
      *(float4*)&wz[4 * i] = s1[i];
      *(float4*)&wn[4 * i] = s2[i];
    }
  }
  float br_ = bhh[lane], bz_ = bhh[64 + lane], bn_ = bhh[128 + lane];

  const float* gbase = gi + ((size_t)b * SS * NN + (size_t)n) * 192;  // +t*NN*192
  // depth-2 software pipeline on gi loads
  float gir = gbase[lane], giz = gbase[64 + lane], gin = gbase[128 + lane];
  const float* g1 = gbase + (size_t)NN * 192;
  float pir = g1[lane], piz = g1[64 + lane], pin = g1[128 + lane];
  float hj = 0.f;

#pragma unroll 1
  for (int t = 0; t < SS; ++t) {
    float qir = 0.f, qiz = 0.f, qin = 0.f;
    if (t + 2 < SS) {
      const float* g2 = gbase + (size_t)(t + 2) * NN * 192;
      qir = g2[lane]; qiz = g2[64 + lane]; qin = g2[128 + lane];
    }
    float ar0 = br_, ar1 = 0.f, az0 = bz_, az1 = 0.f, an0 = bn_, an1 = 0.f;
#pragma unroll
    for (int k = 0; k < HH; k += 2) {
      float h0 = readlane_f(hj, k), h1 = readlane_f(hj, k + 1);
      ar0 += h0 * wr[k];     az0 += h0 * wz[k];     an0 += h0 * wn[k];
      ar1 += h1 * wr[k + 1]; az1 += h1 * wz[k + 1]; an1 += h1 * wn[k + 1];
    }
    float r  = sigmoidf_(gir + ar0 + ar1);
    float z  = sigmoidf_(giz + az0 + az1);
    float nn_ = tanhf(gin + r * (an0 + an1));
    hj = (1.f - z) * nn_ + z * hj;
    gir = pir; giz = piz; gin = pin;
    pir = qir; piz = qiz; pin = qin;
  }

  // ---- fused heads: lanes 0..31 = order head, 32..63 = demand head ----
  int half = lane >> 5, jp = lane & 31;
  const float* W1 = half ? dW1 : oW1;
  const float* b1 = half ? db1 : ob1;
  const float* W2 = half ? dW2 : oW2;
  const float* b2 = half ? db2 : ob2;
  float wv[HH];
#pragma unroll
  for (int i = 0; i < HH / 4; ++i)
    *(float4*)&wv[4 * i] = ((const float4*)(W1 + jp * HH))[i];
  float acc = b1[jp];
#pragma unroll
  for (int k = 0; k < HH; ++k)
    acc += readlane_f(hj, k) * wv[k];            // broadcast from own h copy
  float val = fmaxf(acc, 0.f) * W2[jp];
  val += __shfl_down(val, 16, 32);
  val += __shfl_down(val, 8, 32);
  val += __shfl_down(val, 4, 32);
  val += __shfl_down(val, 2, 32);
  val += __shfl_down(val, 1, 32);
  if (jp == 0) out[half * (BB * NN) + seq] = val + b2[0];
}

// ---------------- fallback GRU (used if ws too small for gi) -----------------
__global__ __launch_bounds__(192, 3) void gru_fused_kernel(
    const float* __restrict__ hbuf,
    const float* __restrict__ Wih, const float* __restrict__ Whh,
    const float* __restrict__ bih, const float* __restrict__ bhh,
    const float* __restrict__ oW1, const float* __restrict__ ob1,
    const float* __restrict__ oW2, const float* __restrict__ ob2,
    const float* __restrict__ dW1, const float* __restrict__ db1,
    const float* __restrict__ dW2, const float* __restrict__ db2,
    float* __restrict__ out) {
  __shared__ float gi_sh[SS * 3 * HH];   // 48 KB  [t][gate][j]
  __shared__ float exch[2][3][HH];       // double-buffered gh exchange

  int lane = threadIdx.x & 63;
  int g = (int)threadIdx.x >> 6;
  int seq = blockIdx.x;
  int b = seq >> 7, n = seq & (NN - 1);
  const float* xbase = hbuf + ((size_t)b * SS * NN + (size_t)n) * HH;

  {
    float w[HH];
    const float4* wsrc = (const float4*)(Wih + (size_t)(g * 64 + lane) * HH);
#pragma unroll
    for (int i = 0; i < HH / 4; ++i) *(float4*)&w[4 * i] = wsrc[i];
    float bias = bih[g * 64 + lane];
#pragma unroll 2
    for (int t = 0; t < SS; ++t) {
      const float* xr = xbase + (size_t)t * NN * HH;
      float a0 = bias, a1 = 0.f, a2 = 0.f, a3 = 0.f;
#pragma unroll
      for (int k = 0; k < HH; k += 4) {
        float4 xb = *(const float4*)(xr + k);
        a0 += xb.x * w[k + 0];
        a1 += xb.y * w[k + 1];
        a2 += xb.z * w[k + 2];
        a3 += xb.w * w[k + 3];
      }
      gi_sh[(t * 3 + g) * HH + lane] = (a0 + a1) + (a2 + a3);
    }
  }

  float whh[HH];
  {
    const float4* wsrc = (const float4*)(Whh + (size_t)(g * 64 + lane) * HH);
#pragma unroll
    for (int i = 0; i < HH / 4; ++i) *(float4*)&whh[4 * i] = wsrc[i];
  }
  float bhg = bhh[g * 64 + lane];
  float hj = 0.f;
  __syncthreads();

#pragma unroll 1
  for (int t = 0; t < SS; ++t) {
    float a0 = bhg, a1 = 0.f, a2 = 0.f, a3 = 0.f;
#pragma unroll
    for (int k = 0; k < HH; k += 4) {
      a0 += readlane_f(hj, k + 0) * whh[k + 0];
      a1 += readlane_f(hj, k + 1) * whh[k + 1];
      a2 += readlane_f(hj, k + 2) * whh[k + 2];
      a3 += readlane_f(hj, k + 3) * whh[k + 3];
    }
    float gh = (a0 + a1) + (a2 + a3);
    int slot = t & 1;
    exch[slot][g][lane] = gh;
    __syncthreads();
    float ghr = exch[slot][0][lane];
    float ghz = exch[slot][1][lane];
    float ghn = exch[slot][2][lane];
    float gir = gi_sh[(t * 3 + 0) * HH + lane];
    float giz = gi_sh[(t * 3 + 1) * HH + lane];
    float gin = gi_sh[(t * 3 + 2) * HH + lane];
    float r  = sigmoidf_(gir + ghr);
    float z  = sigmoidf_(giz + ghz);
    float nn_ = tanhf(gin + r * ghn);
    hj = (1.f - z) * nn_ + z * hj;
  }

  if (g == 0) {
    int half = lane >> 5, jp = lane & 31;
    const float* W1 = half ? dW1 : oW1;
    const float* b1 = half ? db1 : ob1;
    const float* W2 = half ? dW2 : oW2;
    const float* b2 = half ? db2 : ob2;
    float wv[HH];
#pragma unroll
    for (int i = 0; i < HH / 4; ++i)
      *(float4*)&wv[4 * i] = ((const float4*)(W1 + jp * HH))[i];
    float acc = b1[jp];
#pragma unroll
    for (int k = 0; k < HH; ++k)
      acc += readlane_f(hj, k) * wv[k];
    float val = fmaxf(acc, 0.f) * W2[jp];
    val += __shfl_down(val, 16, 32);
    val += __shfl_down(val, 8, 32);
    val += __shfl_down(val, 4, 32);
    val += __shfl_down(val, 2, 32);
    val += __shfl_down(val, 1, 32);
    if (jp == 0) out[half * (BB * NN) + seq] = val + b2[0];
  }
}

// ---------------- launch -----------------------------------------------------
extern "C" void kernel_launch(void* const* d_in, const int* in_sizes, int n_in,
                              void* d_out, int out_size, void* d_ws, size_t ws_size,
                              hipStream_t stream) {
  const float* x       = (const float*)d_in[0];
  const int*   ei      = (const int*)d_in[1];
  const float* in_W    = (const float*)d_in[2];
  const float* in_b    = (const float*)d_in[3];
  const float* gat_Wl  = (const float*)d_in[4];
  const float* gat_bl  = (const float*)d_in[5];
  const float* gat_Wr  = (const float*)d_in[6];
  const float* gat_br  = (const float*)d_in[7];
  const float* gat_att = (const float*)d_in[8];
  const float* gat_bias= (const float*)d_in[9];
  const float* gru_Wih = (const float*)d_in[10];
  const float* gru_Whh = (const float*)d_in[11];
  const float* gru_bih = (const float*)d_in[12];
  const float* gru_bhh = (const float*)d_in[13];
  const float* oh_W1   = (const float*)d_in[14];
  const float* oh_b1   = (const float*)d_in[15];
  const float* oh_W2   = (const float*)d_in[16];
  const float* oh_b2   = (const float*)d_in[17];
  const float* dh_W1   = (const float*)d_in[18];
  const float* dh_b1   = (const float*)d_in[19];
  const float* dh_W2   = (const float*)d_in[20];
  const float* dh_b2   = (const float*)d_in[21];
  float* out = (float*)d_out;

  char* ws = (char*)d_ws;
  size_t hfloats = (size_t)BB * SS * NN * HH;           // 8.39M floats
  float* hbuf = (float*)ws;
  size_t off_csr = hfloats * sizeof(float);
  size_t off_buf = off_csr + (160 + 2 * ET) * sizeof(int);
  off_buf = (off_buf + 255) & ~(size_t)255;             // 256B align
  int* csr_off = (int*)(ws + off_csr);
  int* csr_src = csr_off + 160;
  int* csr_tgt = csr_src + ET;
  float* xlbuf = (float*)(ws + off_buf);
  float* xrbuf = xlbuf + hfloats;
  size_t need_gat = off_buf + 2 * hfloats * sizeof(float);
  bool big_gat = (ws_size >= need_gat);
  // gi buffer overlays xl/xr (dead after the GAT layers): RT*192 floats
  float* gibuf = (float*)(ws + off_buf);
  size_t need_gru = off_buf + (size_t)RT * 192 * sizeof(float);  // ~134 MB
  bool big_gru = (ws_size >= need_gru);

  setup_csr_kernel<<<1, 256, 0, stream>>>(ei, csr_off, csr_src, csr_tgt);
  input_proj_kernel<<<(BB * SS * NN) / (4 * 32), 256, 0, stream>>>(x, in_W, in_b, hbuf);
  for (int l = 0; l < LLAYERS; ++l) {
    if (big_gat) {
      xlxr_kernel<<<RT / 64, 128, 0, stream>>>(
          hbuf, gat_Wl + l * HH * HH, gat_bl + l * HH,
          gat_Wr + l * HH * HH, gat_br + l * HH, xlbuf, xrbuf);
      gat_edge_kernel<<<BB * SS, 256, 0, stream>>>(
          xlbuf, xrbuf, hbuf, csr_off, csr_src, csr_tgt,
          gat_att + l * HH, gat_bias + l * HH);
    } else {
      gat_fused_kernel<<<BB * SS, 256, 0, stream>>>(
          hbuf, hbuf, csr_off, csr_src, csr_tgt,
          gat_Wl + l * HH * HH, gat_bl + l * HH,
          gat_Wr + l * HH * HH, gat_br + l * HH,
          gat_att + l * HH, gat_bias + l * HH);
    }
  }
  if (big_gru) {
    gi_proj_kernel<<<RT / 64, 192, 0, stream>>>(hbuf, gru_Wih, gru_bih, gibuf);
    gru_rec_kernel<<<BB * NN, 64, 0, stream>>>(
        gibuf, gru_Whh, gru_bhh,
        oh_W1, oh_b1, oh_W2, oh_b2, dh_W1, dh_b1, dh_W2, dh_b2, out);
  } else {
    gru_fused_kernel<<<BB * NN, 192, 0, stream>>>(
        hbuf, gru_Wih, gru_Whh, gru_bih, gru_bhh,
        oh_W1, oh_b1, oh_W2, oh_b2, dh_W1, dh_b1, dh_W2, dh_b2, out);
  }
}

// Round 11
// 630.777 us; speedup vs baseline: 1.7642x; 1.0021x over previous
//
#include <hip/hip_runtime.h>
#include <math.h>

#define BB 16
#define SS 64
#define NN 128
#define FF 16
#define HH 64
#define EE 1024
#define ET 1152   // EE + NN self-loops
#define LLAYERS 2
#define XPAD 65   // padded LDS row stride for xl/xr (bank = (s+h)%32 -> ~2-way)
#define HSTRIDE 68 // h_sh row stride: 16B-aligned rows for uniform b128 reads
#define RT (BB * SS * NN)   // 131072 GRU input rows

__device__ __forceinline__ float readlane_f(float v, int k) {
  return __int_as_float(__builtin_amdgcn_readlane(__float_as_int(v), k));
}
// monotonic float<->uint mapping for atomicMax-based float max
__device__ __forceinline__ unsigned flipf(float f) {
  unsigned u = __float_as_uint(f);
  unsigned mask = (u & 0x80000000u) ? 0xFFFFFFFFu : 0x80000000u;
  return u ^ mask;
}
__device__ __forceinline__ float unflipf(unsigned u) {
  unsigned b = (u & 0x80000000u) ? (u ^ 0x80000000u) : ~u;
  return __uint_as_float(b);
}
__device__ __forceinline__ float sigmoidf_(float x) { return 1.f / (1.f + expf(-x)); }

// ---------------- CSR setup (graph is identical for every (b,s)) -------------
__global__ void setup_csr_kernel(const int* __restrict__ ei,
                                 int* __restrict__ off,
                                 int* __restrict__ csrc,
                                 int* __restrict__ ctgt) {
  __shared__ int deg[NN], cur[NN], offs[NN + 1];
  int tid = threadIdx.x;
  if (tid < NN) deg[tid] = 0;
  __syncthreads();
  for (int e = tid; e < ET; e += 256) {
    int tg = (e < EE) ? ei[EE + e] : (e - EE);
    atomicAdd(&deg[tg], 1);
  }
  __syncthreads();
  if (tid == 0) {
    int s = 0;
    for (int i = 0; i < NN; ++i) { offs[i] = s; s += deg[i]; }
    offs[NN] = s;
  }
  __syncthreads();
  if (tid < NN) cur[tid] = offs[tid];
  if (tid <= NN) off[tid] = offs[tid];
  __syncthreads();
  for (int e = tid; e < ET; e += 256) {
    int sv, tg;
    if (e < EE) { sv = ei[e]; tg = ei[EE + e]; }
    else        { sv = e - EE; tg = e - EE; }
    int pos = atomicAdd(&cur[tg], 1);
    csrc[pos] = sv;
    ctgt[pos] = tg;
  }
}

// ---------------- input projection: h = x @ W^T + b --------------------------
__global__ __launch_bounds__(256) void input_proj_kernel(
    const float* __restrict__ x, const float* __restrict__ W,
    const float* __restrict__ bvec, float* __restrict__ h) {
  int lane = threadIdx.x & 63;
  int wid = threadIdx.x >> 6;
  float wreg[FF];
#pragma unroll
  for (int i = 0; i < FF / 4; ++i)
    *(float4*)&wreg[4 * i] = ((const float4*)(W + lane * FF))[i];
  float bias = bvec[lane];
  int row0 = __builtin_amdgcn_readfirstlane((blockIdx.x * 4 + wid) * 32);
#pragma unroll 2
  for (int r = 0; r < 32; ++r) {
    int row = row0 + r;
    const float* xr = x + row * FF;
    float acc = bias;
#pragma unroll
    for (int f = 0; f < FF; ++f) acc += xr[f] * wreg[f];
    h[row * HH + lane] = acc;
  }
}

// ---------------- FUSED GAT layer: GEMM-in-LDS + edges + softmax + gather ----
// R11: fuses xlxr into gat_edge. Rationale (calibrated R6-R10 models):
// the split path cost ~380us/iter across 4 dispatches: xl/xr took a 134MB
// HBM round-trip and were LDS-staged TWICE. Here one 512-thread block per
// (b,s): stage h once (row stride 68, 16B-aligned) -> 8 waves compute
// xl/xr DIRECTLY into LDS (wave w: matrix w>>2, rows (w&3)*32..+32; hybrid
// operand delivery: k[0,32) uniform ds_read_b128 on the DS pipe, k[32,64)
// readlane from split-h regs on the VALU pipe; wreg64+hreg32 ~ 110 VGPR
// < the 128 occupancy step) -> proven pass1/exp/gather on in-LDS xl/xr.
// LDS 111KB -> 1 block/CU, 8 waves = 2/SIMD. In-place: block owns its
// 32KB h slice (read at start, overwritten by gather at end).
__global__ __launch_bounds__(512) void gat_fused2_kernel(
    float* __restrict__ hio,
    const int* __restrict__ csr_off, const int* __restrict__ csr_src,
    const int* __restrict__ csr_tgt,
    const float* __restrict__ Wl, const float* __restrict__ bl,
    const float* __restrict__ Wr, const float* __restrict__ br,
    const float* __restrict__ att, const float* __restrict__ bo) {
  __shared__ float h_sh[NN * HSTRIDE];   // 34.8 KB
  __shared__ float xl_sh[NN * XPAD];     // 33.3 KB
  __shared__ float xr_sh[NN * XPAD];     // 33.3 KB
  __shared__ float p_sh[ET];             // 4.6 KB
  __shared__ int st_sh[ET];              // 4.6 KB
  __shared__ unsigned m_sh[NN];          // 0.5 KB  -> 111 KB total
  int tid = threadIdx.x, lane = tid & 63, wid = tid >> 6;   // 8 waves
  int base = blockIdx.x * (NN * HH);

  // stage h: 2048 float4 coalesced -> 16B-aligned padded rows
  {
    const float4* src4 = (const float4*)(hio + base);
#pragma unroll
    for (int i = 0; i < 4; ++i) {
      int idx = i * 512 + tid;
      int r = idx >> 4, c = idx & 15;
      *(float4*)&h_sh[r * HSTRIDE + c * 4] = src4[idx];
    }
  }
  for (int i = tid; i < ET; i += 512)
    st_sh[i] = csr_src[i] | (csr_tgt[i] << 16);
  if (tid < NN) m_sh[tid] = 0u;
  __syncthreads();

  // ---- GEMM phase: xl/xr into LDS ----
  {
    int mat = wid >> 2;                  // 0 -> xl/Wl, 1 -> xr/Wr
    const float* W  = mat ? Wr : Wl;
    const float* bv = mat ? br : bl;
    float* outsh    = mat ? xr_sh : xl_sh;
    float wreg[HH];
    {
      const float4* ws_ = (const float4*)(W + (size_t)lane * HH);
#pragma unroll
      for (int i = 0; i < HH / 4; ++i) *(float4*)&wreg[4 * i] = ws_[i];
    }
    float bias = bv[lane];
    int r0 = (wid & 3) * 32;
    float hreg[32];                      // row r0+(lane&31), k in [32,64)
    {
      const float* hr = &h_sh[(r0 + (lane & 31)) * HSTRIDE + 32];
#pragma unroll
      for (int i = 0; i < 8; ++i)
        *(float4*)&hreg[4 * i] = *(const float4*)&hr[4 * i];
    }
#pragma unroll 1
    for (int r = 0; r < 32; ++r) {
      const float* hrow = &h_sh[(r0 + r) * HSTRIDE];
      float a0 = bias, a1 = 0.f, a2 = 0.f, a3 = 0.f;
      // k-lo via uniform DS broadcast (DS pipe)
#pragma unroll
      for (int k = 0; k < 32; k += 4) {
        float4 hb = *(const float4*)&hrow[k];
        a0 += hb.x * wreg[k + 0];
        a1 += hb.y * wreg[k + 1];
        a2 += hb.z * wreg[k + 2];
        a3 += hb.w * wreg[k + 3];
      }
      // k-hi via readlane (VALU pipe)
#pragma unroll
      for (int q = 0; q < 32; q += 4) {
        a0 += readlane_f(hreg[q + 0], r) * wreg[32 + q + 0];
        a1 += readlane_f(hreg[q + 1], r) * wreg[32 + q + 1];
        a2 += readlane_f(hreg[q + 2], r) * wreg[32 + q + 2];
        a3 += readlane_f(hreg[q + 3], r) * wreg[32 + q + 3];
      }
      // lanes write consecutive j at (row*65+j): banks (row+j)%32 distinct
      outsh[(r0 + r) * XPAD + lane] = (a0 + a1) + (a2 + a3);
    }
  }
  __syncthreads();

  // ---- pass 1: thread-per-edge attention logit + segment max ----
#pragma unroll 1
  for (int e = tid; e < ET; e += 512) {
    int st = st_sh[e];
    int s = st & 0xffff, tg = st >> 16;
    const float* xlr = xl_sh + s * XPAD;
    const float* xrr = xr_sh + tg * XPAD;
    float a0 = 0.f, a1 = 0.f, a2 = 0.f, a3 = 0.f;
#pragma unroll
    for (int h = 0; h < HH; h += 4) {
      float v0 = xlr[h + 0] + xrr[h + 0]; v0 = (v0 > 0.f) ? v0 : 0.2f * v0;
      float v1 = xlr[h + 1] + xrr[h + 1]; v1 = (v1 > 0.f) ? v1 : 0.2f * v1;
      float v2 = xlr[h + 2] + xrr[h + 2]; v2 = (v2 > 0.f) ? v2 : 0.2f * v2;
      float v3 = xlr[h + 3] + xrr[h + 3]; v3 = (v3 > 0.f) ? v3 : 0.2f * v3;
      a0 += v0 * att[h + 0];
      a1 += v1 * att[h + 1];
      a2 += v2 * att[h + 2];
      a3 += v3 * att[h + 3];
    }
    float a = (a0 + a1) + (a2 + a3);
    p_sh[e] = a;
    atomicMax(&m_sh[tg], flipf(a));
  }
  __syncthreads();

  // ---- pass 2: stabilized exp ----
  for (int e = tid; e < ET; e += 512) {
    int tg = st_sh[e] >> 16;
    p_sh[e] = expf(p_sh[e] - unflipf(m_sh[tg]));
  }
  __syncthreads();

  // ---- gather: wave per target node, CSR-contiguous edge segment ----
  float bo_l = bo[lane];
#pragma unroll 1
  for (int n = wid; n < NN; n += 8) {
    int o0 = __builtin_amdgcn_readfirstlane(csr_off[n]);
    int o1 = __builtin_amdgcn_readfirstlane(csr_off[n + 1]);
    float acc = 0.f, z = 0.f;
    for (int i = o0; i < o1; ++i) {
      float p = p_sh[i];
      int s = st_sh[i] & 0xffff;
      acc += p * xl_sh[s * XPAD + lane];
      z += p;
    }
    float o = acc / z + bo_l;
    hio[base + n * HH + lane] = fmaxf(o, 0.f);
  }
}

// ---------------- GRU stage A: gi = hbuf @ Wih^T + bih  (batched GEMM) -------
// R10 hybrid operand delivery (best measured of 3 designs: 124us; DS-only
// 121, readlane-only 144 -> ~120us structural floor for this op).
__global__ __launch_bounds__(192) void gi_proj_kernel(
    const float* __restrict__ hin, const float* __restrict__ Wih,
    const float* __restrict__ bih, float* __restrict__ gi) {
  __shared__ float lsh[64 * 68];       // 17.4 KB staging (live throughout)
  int tid = threadIdx.x;
  int j = tid & 63;
  int g = tid >> 6;                    // gate wave 0..2
  int row0 = blockIdx.x * 64;
  {
    const float4* src4 = (const float4*)(hin + (size_t)row0 * HH);
#pragma unroll 1
    for (int i = tid; i < 1024; i += 192) {
      int r = i >> 4, c = i & 15;
      *(float4*)&lsh[r * 68 + c * 4] = src4[i];
    }
  }
  float wreg[HH];
  {
    const float4* ws_ = (const float4*)(Wih + (size_t)(g * 64 + j) * HH);
#pragma unroll
    for (int i = 0; i < HH / 4; ++i) *(float4*)&wreg[4 * i] = ws_[i];
  }
  float bias = bih[g * 64 + j];
  int rloc = j & 31;
  __syncthreads();

#pragma unroll 1
  for (int b = 0; b < 2; ++b) {
    float hreg[32];                    // row rloc of batch b, k in [32,64)
    {
      const float* hr = &lsh[(b * 32 + rloc) * 68 + 32];
#pragma unroll
      for (int i = 0; i < 8; ++i)
        *(float4*)&hreg[4 * i] = *(const float4*)&hr[4 * i];
    }
#pragma unroll 1
    for (int r = 0; r < 32; ++r) {
      const float* hrow = &lsh[(b * 32 + r) * 68];
      float a0 = bias, a1 = 0.f, a2 = 0.f, a3 = 0.f;
#pragma unroll
      for (int k = 0; k < 32; k += 4) {
        float4 hb = *(const float4*)&hrow[k];
        a0 += hb.x * wreg[k + 0];
        a1 += hb.y * wreg[k + 1];
        a2 += hb.z * wreg[k + 2];
        a3 += hb.w * wreg[k + 3];
      }
#pragma unroll
      for (int q = 0; q < 32; q += 4) {
        a0 += readlane_f(hreg[q + 0], r) * wreg[32 + q + 0];
        a1 += readlane_f(hreg[q + 1], r) * wreg[32 + q + 1];
        a2 += readlane_f(hreg[q + 2], r) * wreg[32 + q + 2];
        a3 += readlane_f(hreg[q + 3], r) * wreg[32 + q + 3];
      }
      gi[(size_t)(row0 + b * 32 + r) * 192 + g * 64 + j] = (a0 + a1) + (a2 + a3);
    }
  }
}

// ---------------- GRU stage B: recurrence, one wave per sequence -------------
// R3 configuration (best-evidenced: ~90 us, no spill). 2048 blocks x 64
// threads; zero barriers, zero cross-wave traffic. Lane j holds Whh rows
// {j, 64+j, 128+j} (192 floats). h broadcast = v_readlane of the wave's own
// hj. gi streamed with depth-2 prefetch. 2048 waves chip-resident.
__global__ __launch_bounds__(64, 2) void gru_rec_kernel(
    const float* __restrict__ gi,
    const float* __restrict__ Whh, const float* __restrict__ bhh,
    const float* __restrict__ oW1, const float* __restrict__ ob1,
    const float* __restrict__ oW2, const float* __restrict__ ob2,
    const float* __restrict__ dW1, const float* __restrict__ db1,
    const float* __restrict__ dW2, const float* __restrict__ db2,
    float* __restrict__ out) {
  int lane = threadIdx.x;                      // 0..63
  int seq = blockIdx.x;                        // b*N + n
  int b = seq >> 7, n = seq & (NN - 1);

  float wr[HH], wz[HH], wn[HH];
  {
    const float4* s0 = (const float4*)(Whh + (size_t)(0 * 64 + lane) * HH);
    const float4* s1 = (const float4*)(Whh + (size_t)(1 * 64 + lane) * HH);
    const float4* s2 = (const float4*)(Whh + (size_t)(2 * 64 + lane) * HH);
#pragma unroll
    for (int i = 0; i < HH / 4; ++i) {
      *(float4*)&wr[4 * i] = s0[i];
      *(float4*)&wz[4 * i] = s1[i];
      *(float4*)&wn[4 * i] = s2[i];
    }
  }
  float br_ = bhh[lane], bz_ = bhh[64 + lane], bn_ = bhh[128 + lane];

  const float* gbase = gi + ((size_t)b * SS * NN + (size_t)n) * 192;  // +t*NN*192
  // depth-2 software pipeline on gi loads
  float gir = gbase[lane], giz = gbase[64 + lane], gin = gbase[128 + lane];
  const float* g1 = gbase + (size_t)NN * 192;
  float pir = g1[lane], piz = g1[64 + lane], pin = g1[128 + lane];
  float hj = 0.f;

#pragma unroll 1
  for (int t = 0; t < SS; ++t) {
    float qir = 0.f, qiz = 0.f, qin = 0.f;
    if (t + 2 < SS) {
      const float* g2 = gbase + (size_t)(t + 2) * NN * 192;
      qir = g2[lane]; qiz = g2[64 + lane]; qin = g2[128 + lane];
    }
    float ar0 = br_, ar1 = 0.f, az0 = bz_, az1 = 0.f, an0 = bn_, an1 = 0.f;
#pragma unroll
    for (int k = 0; k < HH; k += 2) {
      float h0 = readlane_f(hj, k), h1 = readlane_f(hj, k + 1);
      ar0 += h0 * wr[k];     az0 += h0 * wz[k];     an0 += h0 * wn[k];
      ar1 += h1 * wr[k + 1]; az1 += h1 * wz[k + 1]; an1 += h1 * wn[k + 1];
    }
    float r  = sigmoidf_(gir + ar0 + ar1);
    float z  = sigmoidf_(giz + az0 + az1);
    float nn_ = tanhf(gin + r * (an0 + an1));
    hj = (1.f - z) * nn_ + z * hj;
    gir = pir; giz = piz; gin = pin;
    pir = qir; piz = qiz; pin = qin;
  }

  // ---- fused heads: lanes 0..31 = order head, 32..63 = demand head ----
  int half = lane >> 5, jp = lane & 31;
  const float* W1 = half ? dW1 : oW1;
  const float* b1 = half ? db1 : ob1;
  const float* W2 = half ? dW2 : oW2;
  const float* b2 = half ? db2 : ob2;
  float wv[HH];
#pragma unroll
  for (int i = 0; i < HH / 4; ++i)
    *(float4*)&wv[4 * i] = ((const float4*)(W1 + jp * HH))[i];
  float acc = b1[jp];
#pragma unroll
  for (int k = 0; k < HH; ++k)
    acc += readlane_f(hj, k) * wv[k];            // broadcast from own h copy
  float val = fmaxf(acc, 0.f) * W2[jp];
  val += __shfl_down(val, 16, 32);
  val += __shfl_down(val, 8, 32);
  val += __shfl_down(val, 4, 32);
  val += __shfl_down(val, 2, 32);
  val += __shfl_down(val, 1, 32);
  if (jp == 0) out[half * (BB * NN) + seq] = val + b2[0];
}

// ---------------- fallback GRU (used if ws too small for gi) -----------------
__global__ __launch_bounds__(192, 3) void gru_fused_kernel(
    const float* __restrict__ hbuf,
    const float* __restrict__ Wih, const float* __restrict__ Whh,
    const float* __restrict__ bih, const float* __restrict__ bhh,
    const float* __restrict__ oW1, const float* __restrict__ ob1,
    const float* __restrict__ oW2, const float* __restrict__ ob2,
    const float* __restrict__ dW1, const float* __restrict__ db1,
    const float* __restrict__ dW2, const float* __restrict__ db2,
    float* __restrict__ out) {
  __shared__ float gi_sh[SS * 3 * HH];   // 48 KB  [t][gate][j]
  __shared__ float exch[2][3][HH];       // double-buffered gh exchange

  int lane = threadIdx.x & 63;
  int g = (int)threadIdx.x >> 6;
  int seq = blockIdx.x;
  int b = seq >> 7, n = seq & (NN - 1);
  const float* xbase = hbuf + ((size_t)b * SS * NN + (size_t)n) * HH;

  {
    float w[HH];
    const float4* wsrc = (const float4*)(Wih + (size_t)(g * 64 + lane) * HH);
#pragma unroll
    for (int i = 0; i < HH / 4; ++i) *(float4*)&w[4 * i] = wsrc[i];
    float bias = bih[g * 64 + lane];
#pragma unroll 2
    for (int t = 0; t < SS; ++t) {
      const float* xr = xbase + (size_t)t * NN * HH;
      float a0 = bias, a1 = 0.f, a2 = 0.f, a3 = 0.f;
#pragma unroll
      for (int k = 0; k < HH; k += 4) {
        float4 xb = *(const float4*)(xr + k);
        a0 += xb.x * w[k + 0];
        a1 += xb.y * w[k + 1];
        a2 += xb.z * w[k + 2];
        a3 += xb.w * w[k + 3];
      }
      gi_sh[(t * 3 + g) * HH + lane] = (a0 + a1) + (a2 + a3);
    }
  }

  float whh[HH];
  {
    const float4* wsrc = (const float4*)(Whh + (size_t)(g * 64 + lane) * HH);
#pragma unroll
    for (int i = 0; i < HH / 4; ++i) *(float4*)&whh[4 * i] = wsrc[i];
  }
  float bhg = bhh[g * 64 + lane];
  float hj = 0.f;
  __syncthreads();

#pragma unroll 1
  for (int t = 0; t < SS; ++t) {
    float a0 = bhg, a1 = 0.f, a2 = 0.f, a3 = 0.f;
#pragma unroll
    for (int k = 0; k < HH; k += 4) {
      a0 += readlane_f(hj, k + 0) * whh[k + 0];
      a1 += readlane_f(hj, k + 1) * whh[k + 1];
      a2 += readlane_f(hj, k + 2) * whh[k + 2];
      a3 += readlane_f(hj, k + 3) * whh[k + 3];
    }
    float gh = (a0 + a1) + (a2 + a3);
    int slot = t & 1;
    exch[slot][g][lane] = gh;
    __syncthreads();
    float ghr = exch[slot][0][lane];
    float ghz = exch[slot][1][lane];
    float ghn = exch[slot][2][lane];
    float gir = gi_sh[(t * 3 + 0) * HH + lane];
    float giz = gi_sh[(t * 3 + 1) * HH + lane];
    float gin = gi_sh[(t * 3 + 2) * HH + lane];
    float r  = sigmoidf_(gir + ghr);
    float z  = sigmoidf_(giz + ghz);
    float nn_ = tanhf(gin + r * ghn);
    hj = (1.f - z) * nn_ + z * hj;
  }

  if (g == 0) {
    int half = lane >> 5, jp = lane & 31;
    const float* W1 = half ? dW1 : oW1;
    const float* b1 = half ? db1 : ob1;
    const float* W2 = half ? dW2 : oW2;
    const float* b2 = half ? db2 : ob2;
    float wv[HH];
#pragma unroll
    for (int i = 0; i < HH / 4; ++i)
      *(float4*)&wv[4 * i] = ((const float4*)(W1 + jp * HH))[i];
    float acc = b1[jp];
#pragma unroll
    for (int k = 0; k < HH; ++k)
      acc += readlane_f(hj, k) * wv[k];
    float val = fmaxf(acc, 0.f) * W2[jp];
    val += __shfl_down(val, 16, 32);
    val += __shfl_down(val, 8, 32);
    val += __shfl_down(val, 4, 32);
    val += __shfl_down(val, 2, 32);
    val += __shfl_down(val, 1, 32);
    if (jp == 0) out[half * (BB * NN) + seq] = val + b2[0];
  }
}

// ---------------- launch -----------------------------------------------------
extern "C" void kernel_launch(void* const* d_in, const int* in_sizes, int n_in,
                              void* d_out, int out_size, void* d_ws, size_t ws_size,
                              hipStream_t stream) {
  const float* x       = (const float*)d_in[0];
  const int*   ei      = (const int*)d_in[1];
  const float* in_W    = (const float*)d_in[2];
  const float* in_b    = (const float*)d_in[3];
  const float* gat_Wl  = (const float*)d_in[4];
  const float* gat_bl  = (const float*)d_in[5];
  const float* gat_Wr  = (const float*)d_in[6];
  const float* gat_br  = (const float*)d_in[7];
  const float* gat_att = (const float*)d_in[8];
  const float* gat_bias= (const float*)d_in[9];
  const float* gru_Wih = (const float*)d_in[10];
  const float* gru_Whh = (const float*)d_in[11];
  const float* gru_bih = (const float*)d_in[12];
  const float* gru_bhh = (const float*)d_in[13];
  const float* oh_W1   = (const float*)d_in[14];
  const float* oh_b1   = (const float*)d_in[15];
  const float* oh_W2   = (const float*)d_in[16];
  const float* oh_b2   = (const float*)d_in[17];
  const float* dh_W1   = (const float*)d_in[18];
  const float* dh_b1   = (const float*)d_in[19];
  const float* dh_W2   = (const float*)d_in[20];
  const float* dh_b2   = (const float*)d_in[21];
  float* out = (float*)d_out;

  char* ws = (char*)d_ws;
  size_t hfloats = (size_t)BB * SS * NN * HH;           // 8.39M floats
  float* hbuf = (float*)ws;
  size_t off_csr = hfloats * sizeof(float);
  size_t off_buf = off_csr + (160 + 2 * ET) * sizeof(int);
  off_buf = (off_buf + 255) & ~(size_t)255;             // 256B align
  int* csr_off = (int*)(ws + off_csr);
  int* csr_src = csr_off + 160;
  int* csr_tgt = csr_src + ET;
  // gi buffer lives after the CSR block: RT*192 floats (~100 MB)
  float* gibuf = (float*)(ws + off_buf);
  size_t need_gru = off_buf + (size_t)RT * 192 * sizeof(float);
  bool big_gru = (ws_size >= need_gru);

  setup_csr_kernel<<<1, 256, 0, stream>>>(ei, csr_off, csr_src, csr_tgt);
  input_proj_kernel<<<(BB * SS * NN) / (4 * 32), 256, 0, stream>>>(x, in_W, in_b, hbuf);
  for (int l = 0; l < LLAYERS; ++l) {
    gat_fused2_kernel<<<BB * SS, 512, 0, stream>>>(
        hbuf, csr_off, csr_src, csr_tgt,
        gat_Wl + l * HH * HH, gat_bl + l * HH,
        gat_Wr + l * HH * HH, gat_br + l * HH,
        gat_att + l * HH, gat_bias + l * HH);
  }
  if (big_gru) {
    gi_proj_kernel<<<RT / 64, 192, 0, stream>>>(hbuf, gru_Wih, gru_bih, gibuf);
    gru_rec_kernel<<<BB * NN, 64, 0, stream>>>(
        gibuf, gru_Whh, gru_bhh,
        oh_W1, oh_b1, oh_W2, oh_b2, dh_W1, dh_b1, dh_W2, dh_b2, out);
  } else {
    gru_fused_kernel<<<BB * NN, 192, 0, stream>>>(
        hbuf, gru_Wih, gru_Whh, gru_bih, gru_bhh,
        oh_W1, oh_b1, oh_W2, oh_b2, dh_W1, dh_b1, dh_W2, dh_b2, out);
  }
}

// Round 12
// 602.128 us; speedup vs baseline: 1.8481x; 1.0476x over previous
//
#include <hip/hip_runtime.h>
#include <math.h>

#define BB 16
#define SS 64
#define NN 128
#define FF 16
#define HH 64
#define EE 1024
#define ET 1152   // EE + NN self-loops
#define LLAYERS 2
#define XPAD 65   // padded LDS row stride for xl/xr (bank = (s+h)%32)
#define RT (BB * SS * NN)   // 131072 GRU input rows

__device__ __forceinline__ float readlane_f(float v, int k) {
  return __int_as_float(__builtin_amdgcn_readlane(__float_as_int(v), k));
}
// monotonic float<->uint mapping for atomicMax-based float max
__device__ __forceinline__ unsigned flipf(float f) {
  unsigned u = __float_as_uint(f);
  unsigned mask = (u & 0x80000000u) ? 0xFFFFFFFFu : 0x80000000u;
  return u ^ mask;
}
__device__ __forceinline__ float unflipf(unsigned u) {
  unsigned b = (u & 0x80000000u) ? (u ^ 0x80000000u) : ~u;
  return __uint_as_float(b);
}
__device__ __forceinline__ float sigmoidf_(float x) { return 1.f / (1.f + expf(-x)); }

// ---------------- CSR setup (graph is identical for every (b,s)) -------------
__global__ void setup_csr_kernel(const int* __restrict__ ei,
                                 int* __restrict__ off,
                                 int* __restrict__ csrc,
                                 int* __restrict__ ctgt) {
  __shared__ int deg[NN], cur[NN], offs[NN + 1];
  int tid = threadIdx.x;
  if (tid < NN) deg[tid] = 0;
  __syncthreads();
  for (int e = tid; e < ET; e += 256) {
    int tg = (e < EE) ? ei[EE + e] : (e - EE);
    atomicAdd(&deg[tg], 1);
  }
  __syncthreads();
  if (tid == 0) {
    int s = 0;
    for (int i = 0; i < NN; ++i) { offs[i] = s; s += deg[i]; }
    offs[NN] = s;
  }
  __syncthreads();
  if (tid < NN) cur[tid] = offs[tid];
  if (tid <= NN) off[tid] = offs[tid];
  __syncthreads();
  for (int e = tid; e < ET; e += 256) {
    int sv, tg;
    if (e < EE) { sv = ei[e]; tg = ei[EE + e]; }
    else        { sv = e - EE; tg = e - EE; }
    int pos = atomicAdd(&cur[tg], 1);
    csrc[pos] = sv;
    ctgt[pos] = tg;
  }
}

// ---------------- input projection: h = x @ W^T + b --------------------------
__global__ __launch_bounds__(256) void input_proj_kernel(
    const float* __restrict__ x, const float* __restrict__ W,
    const float* __restrict__ bvec, float* __restrict__ h) {
  int lane = threadIdx.x & 63;
  int wid = threadIdx.x >> 6;
  float wreg[FF];
#pragma unroll
  for (int i = 0; i < FF / 4; ++i)
    *(float4*)&wreg[4 * i] = ((const float4*)(W + lane * FF))[i];
  float bias = bvec[lane];
  int row0 = __builtin_amdgcn_readfirstlane((blockIdx.x * 4 + wid) * 32);
#pragma unroll 2
  for (int r = 0; r < 32; ++r) {
    int row = row0 + r;
    const float* xr = x + row * FF;
    float acc = bias;
#pragma unroll
    for (int f = 0; f < FF; ++f) acc += xr[f] * wreg[f];
    h[row * HH + lane] = acc;
  }
}

// ---------------- GAT kernel A: xl = h@Wl^T+bl, xr = h@Wr^T+br ---------------
// R6 configuration (best measured total: 605us). C=1 spill-proof variant:
// 128-thread blocks = 2 waves; wave 0 owns xl (Wl), wave 1 owns xr (Wr).
// ONE 64-float weight row per lane -> natural VGPR need ~90 < the 128 cliff.
// h rows staged cooperatively into LDS (coalesced float4), matvec operand =
// uniform ds_read_b128 broadcast (conflict-free).
__global__ __launch_bounds__(128) void xlxr_kernel(
    const float* __restrict__ hin,
    const float* __restrict__ Wl, const float* __restrict__ bl,
    const float* __restrict__ Wr, const float* __restrict__ br,
    float* __restrict__ xl, float* __restrict__ xr) {
  __shared__ float hsh[64 * HH];       // 16 KB: 64 staged h rows
  int tid = threadIdx.x;
  int j = tid & 63;                    // output column
  int w = tid >> 6;                    // 0 -> xl, 1 -> xr
  int row0 = blockIdx.x * 64;
  {
    const float4* src4 = (const float4*)(hin + (size_t)row0 * HH);
    float4* dst4 = (float4*)hsh;
#pragma unroll
    for (int i = 0; i < 8; ++i)
      dst4[i * 128 + tid] = src4[i * 128 + tid];   // coalesced 2 KB per instr
  }
  __syncthreads();
  const float* W  = w ? Wr : Wl;
  const float* bv = w ? br : bl;
  float* outp     = w ? xr : xl;
  float wreg[HH];
  {
    const float4* ws_ = (const float4*)(W + (size_t)j * HH);
#pragma unroll
    for (int i = 0; i < HH / 4; ++i) *(float4*)&wreg[4 * i] = ws_[i];
  }
  float bias = bv[j];
#pragma unroll 1
  for (int r = 0; r < 64; ++r) {
    float a0 = bias, a1 = 0.f, a2 = 0.f, a3 = 0.f;
#pragma unroll
    for (int k = 0; k < HH; k += 4) {
      float4 hb = *(const float4*)&hsh[r * HH + k];   // uniform broadcast read
      a0 += hb.x * wreg[k + 0];
      a1 += hb.y * wreg[k + 1];
      a2 += hb.z * wreg[k + 2];
      a3 += hb.w * wreg[k + 3];
    }
    outp[(size_t)(row0 + r) * HH + j] = (a0 + a1) + (a2 + a3);  // 256 B coalesced
  }
}

// ---------------- GAT kernel B: edge logits + softmax + aggregate ------------
__global__ __launch_bounds__(256) void gat_edge_kernel(
    const float* __restrict__ xl_g, const float* __restrict__ xr_g,
    float* __restrict__ hout,
    const int* __restrict__ csr_off, const int* __restrict__ csr_src,
    const int* __restrict__ csr_tgt,
    const float* __restrict__ att, const float* __restrict__ bo) {
  __shared__ float xl_sh[NN * XPAD];   // 33.3 KB
  __shared__ float xr_sh[NN * XPAD];   // 33.3 KB
  __shared__ float p_sh[ET];
  __shared__ int st_sh[ET];
  __shared__ unsigned m_sh[NN];
  int tid = threadIdx.x, lane = tid & 63, wid = tid >> 6;
  int base = blockIdx.x * (NN * HH);

  // stage xl/xr with padded stride
#pragma unroll 1
  for (int i = tid * 4; i < NN * HH; i += 256 * 4) {
    int row = i >> 6, h = i & 63;
    float4 vl = *(const float4*)(xl_g + base + i);
    float4 vr = *(const float4*)(xr_g + base + i);
    float* dl = xl_sh + row * XPAD + h;
    float* dr = xr_sh + row * XPAD + h;
    dl[0] = vl.x; dl[1] = vl.y; dl[2] = vl.z; dl[3] = vl.w;
    dr[0] = vr.x; dr[1] = vr.y; dr[2] = vr.z; dr[3] = vr.w;
  }
  for (int i = tid; i < ET; i += 256)
    st_sh[i] = csr_src[i] | (csr_tgt[i] << 16);
  if (tid < NN) m_sh[tid] = 0u;
  __syncthreads();

  // pass 1: thread-per-edge attention logit + segment max
#pragma unroll 1
  for (int e = tid; e < ET; e += 256) {
    int st = st_sh[e];
    int s = st & 0xffff, tg = st >> 16;
    const float* xlr = xl_sh + s * XPAD;
    const float* xrr = xr_sh + tg * XPAD;
    float a0 = 0.f, a1 = 0.f, a2 = 0.f, a3 = 0.f;
#pragma unroll
    for (int h = 0; h < HH; h += 4) {
      float v0 = xlr[h + 0] + xrr[h + 0]; v0 = (v0 > 0.f) ? v0 : 0.2f * v0;
      float v1 = xlr[h + 1] + xrr[h + 1]; v1 = (v1 > 0.f) ? v1 : 0.2f * v1;
      float v2 = xlr[h + 2] + xrr[h + 2]; v2 = (v2 > 0.f) ? v2 : 0.2f * v2;
      float v3 = xlr[h + 3] + xrr[h + 3]; v3 = (v3 > 0.f) ? v3 : 0.2f * v3;
      a0 += v0 * att[h + 0];
      a1 += v1 * att[h + 1];
      a2 += v2 * att[h + 2];
      a3 += v3 * att[h + 3];
    }
    float a = (a0 + a1) + (a2 + a3);
    p_sh[e] = a;
    atomicMax(&m_sh[tg], flipf(a));
  }
  __syncthreads();

  // pass 2: stabilized exp
  for (int e = tid; e < ET; e += 256) {
    int tg = st_sh[e] >> 16;
    p_sh[e] = expf(p_sh[e] - unflipf(m_sh[tg]));
  }
  __syncthreads();

  // gather: wave per target node, CSR-contiguous edge segment
  float bo_l = bo[lane];
#pragma unroll 1
  for (int n = wid; n < NN; n += 4) {
    int o0 = __builtin_amdgcn_readfirstlane(csr_off[n]);
    int o1 = __builtin_amdgcn_readfirstlane(csr_off[n + 1]);
    float acc = 0.f, z = 0.f;
    for (int i = o0; i < o1; ++i) {
      float p = p_sh[i];
      int s = st_sh[i] & 0xffff;
      acc += p * xl_sh[s * XPAD + lane];
      z += p;
    }
    float o = acc / z + bo_l;
    hout[base + n * HH + lane] = fmaxf(o, 0.f);
  }
}

// ---------------- fallback fused GAT (used if ws too small) ------------------
__device__ __forceinline__ void gemm_half(
    const float* __restrict__ hin, int base,
    const float* __restrict__ W, const float* __restrict__ bvec,
    float* __restrict__ out_sh, int half, int lane) {
  float wreg[HH];
#pragma unroll
  for (int i = 0; i < HH / 4; ++i)
    *(float4*)&wreg[4 * i] = ((const float4*)(W + lane * HH))[i];
  float bias = bvec[lane];
  int n0 = __builtin_amdgcn_readfirstlane(half * 64);
#pragma unroll 1
  for (int nd = 0; nd < 64; ++nd) {
    int node = n0 + nd;
    const float* hrow = hin + base + node * HH;
    float a0 = bias, a1 = 0.f, a2 = 0.f, a3 = 0.f;
#pragma unroll
    for (int f = 0; f < HH; f += 4) {
      a0 += hrow[f + 0] * wreg[f + 0];
      a1 += hrow[f + 1] * wreg[f + 1];
      a2 += hrow[f + 2] * wreg[f + 2];
      a3 += hrow[f + 3] * wreg[f + 3];
    }
    out_sh[node * HH + lane] = (a0 + a1) + (a2 + a3);
  }
}

__global__ __launch_bounds__(256) void gat_fused_kernel(
    const float* __restrict__ hin, float* __restrict__ hout,
    const int* __restrict__ csr_off, const int* __restrict__ csr_src,
    const int* __restrict__ csr_tgt,
    const float* __restrict__ Wl, const float* __restrict__ bl,
    const float* __restrict__ Wr, const float* __restrict__ br,
    const float* __restrict__ att, const float* __restrict__ bo) {
  __shared__ float xl_sh[NN * HH];
  __shared__ float xr_sh[NN * HH];
  __shared__ float p_sh[ET];
  __shared__ int st_sh[ET];
  __shared__ unsigned m_sh[NN];
  int tid = threadIdx.x, lane = tid & 63, wid = tid >> 6;
  int base = blockIdx.x * (NN * HH);

  for (int i = tid; i < ET; i += 256)
    st_sh[i] = csr_src[i] | (csr_tgt[i] << 16);
  if (tid < NN) m_sh[tid] = 0u;

  if (wid < 2) gemm_half(hin, base, Wl, bl, xl_sh, wid & 1, lane);
  else         gemm_half(hin, base, Wr, br, xr_sh, wid & 1, lane);

  float att_l = att[lane];
  float bo_l = bo[lane];
  __syncthreads();

#pragma unroll 1
  for (int e = wid; e < ET; e += 4) {
    int st = st_sh[e];
    int s = st & 0xffff, tg = st >> 16;
    float v = xl_sh[s * HH + lane] + xr_sh[tg * HH + lane];
    v = (v > 0.f) ? v : 0.2f * v;
    float prod = v * att_l;
#pragma unroll
    for (int mm = 32; mm; mm >>= 1) prod += __shfl_xor(prod, mm);
    if (lane == 0) {
      p_sh[e] = prod;
      atomicMax(&m_sh[tg], flipf(prod));
    }
  }
  __syncthreads();

  for (int e = tid; e < ET; e += 256) {
    int tg = st_sh[e] >> 16;
    p_sh[e] = expf(p_sh[e] - unflipf(m_sh[tg]));
  }
  __syncthreads();

#pragma unroll 1
  for (int n = wid; n < NN; n += 4) {
    int o0 = csr_off[n], o1 = csr_off[n + 1];
    float acc = 0.f, z = 0.f;
    for (int i = o0; i < o1; ++i) {
      float p = p_sh[i];
      int s = st_sh[i] & 0xffff;
      acc += p * xl_sh[s * HH + lane];
      z += p;
    }
    float o = acc / z + bo_l;
    hout[base + n * HH + lane] = fmaxf(o, 0.f);
  }
}

// ---------------- GRU stage A: gi = hbuf @ Wih^T + bih  (batched GEMM) -------
// R6 configuration (best measured of 3 designs: 121us; readlane-only 144,
// hybrid 124 -> ~120us structural floor for this op). C=1: 192-thread
// blocks = 3 gate-waves; wave g, lane j owns output column g*64+j -> ONE
// 64-float Wih row per lane (VGPR=92, no spill). 64 h rows staged
// cooperatively, matvec operand = uniform ds_read_b128 broadcast.
__global__ __launch_bounds__(192) void gi_proj_kernel(
    const float* __restrict__ hin, const float* __restrict__ Wih,
    const float* __restrict__ bih, float* __restrict__ gi) {
  __shared__ float hsh[64 * HH];       // 16 KB
  int tid = threadIdx.x;
  int j = tid & 63;                    // output column within gate
  int g = tid >> 6;                    // gate 0..2
  int row0 = blockIdx.x * 64;
  {
    const float4* src4 = (const float4*)(hin + (size_t)row0 * HH);
    float4* dst4 = (float4*)hsh;
#pragma unroll 1
    for (int i = tid; i < 1024; i += 192)
      dst4[i] = src4[i];               // coalesced
  }
  __syncthreads();
  float wreg[HH];
  {
    const float4* ws_ = (const float4*)(Wih + (size_t)(g * 64 + j) * HH);
#pragma unroll
    for (int i = 0; i < HH / 4; ++i) *(float4*)&wreg[4 * i] = ws_[i];
  }
  float bias = bih[g * 64 + j];
#pragma unroll 1
  for (int r = 0; r < 64; ++r) {
    float a0 = bias, a1 = 0.f, a2 = 0.f, a3 = 0.f;
#pragma unroll
    for (int k = 0; k < HH; k += 4) {
      float4 hb = *(const float4*)&hsh[r * HH + k];   // uniform broadcast read
      a0 += hb.x * wreg[k + 0];
      a1 += hb.y * wreg[k + 1];
      a2 += hb.z * wreg[k + 2];
      a3 += hb.w * wreg[k + 3];
    }
    gi[(size_t)(row0 + r) * 192 + g * 64 + j] = (a0 + a1) + (a2 + a3);
  }
}

// ---------------- GRU stage B: recurrence, one wave per sequence -------------
// R3 configuration (best-evidenced: ~90 us, no spill). 2048 blocks x 64
// threads; zero barriers, zero cross-wave traffic. Lane j holds Whh rows
// {j, 64+j, 128+j} (192 floats). h broadcast = v_readlane of the wave's own
// hj. gi streamed with depth-2 prefetch. 2048 waves chip-resident.
__global__ __launch_bounds__(64, 2) void gru_rec_kernel(
    const float* __restrict__ gi,
    const float* __restrict__ Whh, const float* __restrict__ bhh,
    const float* __restrict__ oW1, const float* __restrict__ ob1,
    const float* __restrict__ oW2, const float* __restrict__ ob2,
    const float* __restrict__ dW1, const float* __restrict__ db1,
    const float* __restrict__ dW2, const float* __restrict__ db2,
    float* __restrict__ out) {
  int lane = threadIdx.x;                      // 0..63
  int seq = blockIdx.x;                        // b*N + n
  int b = seq >> 7, n = seq & (NN - 1);

  float wr[HH], wz[HH], wn[HH];
  {
    const float4* s0 = (const float4*)(Whh + (size_t)(0 * 64 + lane) * HH);
    const float4* s1 = (const float4*)(Whh + (size_t)(1 * 64 + lane) * HH);
    const float4* s2 = (const float4*)(Whh + (size_t)(2 * 64 + lane) * HH);
#pragma unroll
    for (int i = 0; i < HH / 4; ++i) {
      *(float4*)&wr[4 * i] = s0[i];
      *(float4*)&wz[4 * i] = s1[i];
      *(float4*)&wn[4 * i] = s2[i];
    }
  }
  float br_ = bhh[lane], bz_ = bhh[64 + lane], bn_ = bhh[128 + lane];

  const float* gbase = gi + ((size_t)b * SS * NN + (size_t)n) * 192;  // +t*NN*192
  // depth-2 software pipeline on gi loads
  float gir = gbase[lane], giz = gbase[64 + lane], gin = gbase[128 + lane];
  const float* g1 = gbase + (size_t)NN * 192;
  float pir = g1[lane], piz = g1[64 + lane], pin = g1[128 + lane];
  float hj = 0.f;

#pragma unroll 1
  for (int t = 0; t < SS; ++t) {
    float qir = 0.f, qiz = 0.f, qin = 0.f;
    if (t + 2 < SS) {
      const float* g2 = gbase + (size_t)(t + 2) * NN * 192;
      qir = g2[lane]; qiz = g2[64 + lane]; qin = g2[128 + lane];
    }
    float ar0 = br_, ar1 = 0.f, az0 = bz_, az1 = 0.f, an0 = bn_, an1 = 0.f;
#pragma unroll
    for (int k = 0; k < HH; k += 2) {
      float h0 = readlane_f(hj, k), h1 = readlane_f(hj, k + 1);
      ar0 += h0 * wr[k];     az0 += h0 * wz[k];     an0 += h0 * wn[k];
      ar1 += h1 * wr[k + 1]; az1 += h1 * wz[k + 1]; an1 += h1 * wn[k + 1];
    }
    float r  = sigmoidf_(gir + ar0 + ar1);
    float z  = sigmoidf_(giz + az0 + az1);
    float nn_ = tanhf(gin + r * (an0 + an1));
    hj = (1.f - z) * nn_ + z * hj;
    gir = pir; giz = piz; gin = pin;
    pir = qir; piz = qiz; pin = qin;
  }

  // ---- fused heads: lanes 0..31 = order head, 32..63 = demand head ----
  int half = lane >> 5, jp = lane & 31;
  const float* W1 = half ? dW1 : oW1;
  const float* b1 = half ? db1 : ob1;
  const float* W2 = half ? dW2 : oW2;
  const float* b2 = half ? db2 : ob2;
  float wv[HH];
#pragma unroll
  for (int i = 0; i < HH / 4; ++i)
    *(float4*)&wv[4 * i] = ((const float4*)(W1 + jp * HH))[i];
  float acc = b1[jp];
#pragma unroll
  for (int k = 0; k < HH; ++k)
    acc += readlane_f(hj, k) * wv[k];            // broadcast from own h copy
  float val = fmaxf(acc, 0.f) * W2[jp];
  val += __shfl_down(val, 16, 32);
  val += __shfl_down(val, 8, 32);
  val += __shfl_down(val, 4, 32);
  val += __shfl_down(val, 2, 32);
  val += __shfl_down(val, 1, 32);
  if (jp == 0) out[half * (BB * NN) + seq] = val + b2[0];
}

// ---------------- fallback GRU (used if ws too small for gi) -----------------
__global__ __launch_bounds__(192, 3) void gru_fused_kernel(
    const float* __restrict__ hbuf,
    const float* __restrict__ Wih, const float* __restrict__ Whh,
    const float* __restrict__ bih, const float* __restrict__ bhh,
    const float* __restrict__ oW1, const float* __restrict__ ob1,
    const float* __restrict__ oW2, const float* __restrict__ ob2,
    const float* __restrict__ dW1, const float* __restrict__ db1,
    const float* __restrict__ dW2, const float* __restrict__ db2,
    float* __restrict__ out) {
  __shared__ float gi_sh[SS * 3 * HH];   // 48 KB  [t][gate][j]
  __shared__ float exch[2][3][HH];       // double-buffered gh exchange

  int lane = threadIdx.x & 63;
  int g = (int)threadIdx.x >> 6;
  int seq = blockIdx.x;
  int b = seq >> 7, n = seq & (NN - 1);
  const float* xbase = hbuf + ((size_t)b * SS * NN + (size_t)n) * HH;

  {
    float w[HH];
    const float4* wsrc = (const float4*)(Wih + (size_t)(g * 64 + lane) * HH);
#pragma unroll
    for (int i = 0; i < HH / 4; ++i) *(float4*)&w[4 * i] = wsrc[i];
    float bias = bih[g * 64 + lane];
#pragma unroll 2
    for (int t = 0; t < SS; ++t) {
      const float* xr = xbase + (size_t)t * NN * HH;
      float a0 = bias, a1 = 0.f, a2 = 0.f, a3 = 0.f;
#pragma unroll
      for (int k = 0; k < HH; k += 4) {
        float4 xb = *(const float4*)(xr + k);
        a0 += xb.x * w[k + 0];
        a1 += xb.y * w[k + 1];
        a2 += xb.z * w[k + 2];
        a3 += xb.w * w[k + 3];
      }
      gi_sh[(t * 3 + g) * HH + lane] = (a0 + a1) + (a2 + a3);
    }
  }

  float whh[HH];
  {
    const float4* wsrc = (const float4*)(Whh + (size_t)(g * 64 + lane) * HH);
#pragma unroll
    for (int i = 0; i < HH / 4; ++i) *(float4*)&whh[4 * i] = wsrc[i];
  }
  float bhg = bhh[g * 64 + lane];
  float hj = 0.f;
  __syncthreads();

#pragma unroll 1
  for (int t = 0; t < SS; ++t) {
    float a0 = bhg, a1 = 0.f, a2 = 0.f, a3 = 0.f;
#pragma unroll
    for (int k = 0; k < HH; k += 4) {
      a0 += readlane_f(hj, k + 0) * whh[k + 0];
      a1 += readlane_f(hj, k + 1) * whh[k + 1];
      a2 += readlane_f(hj, k + 2) * whh[k + 2];
      a3 += readlane_f(hj, k + 3) * whh[k + 3];
    }
    float gh = (a0 + a1) + (a2 + a3);
    int slot = t & 1;
    exch[slot][g][lane] = gh;
    __syncthreads();
    float ghr = exch[slot][0][lane];
    float ghz = exch[slot][1][lane];
    float ghn = exch[slot][2][lane];
    float gir = gi_sh[(t * 3 + 0) * HH + lane];
    float giz = gi_sh[(t * 3 + 1) * HH + lane];
    float gin = gi_sh[(t * 3 + 2) * HH + lane];
    float r  = sigmoidf_(gir + ghr);
    float z  = sigmoidf_(giz + ghz);
    float nn_ = tanhf(gin + r * ghn);
    hj = (1.f - z) * nn_ + z * hj;
  }

  if (g == 0) {
    int half = lane >> 5, jp = lane & 31;
    const float* W1 = half ? dW1 : oW1;
    const float* b1 = half ? db1 : ob1;
    const float* W2 = half ? dW2 : oW2;
    const float* b2 = half ? db2 : ob2;
    float wv[HH];
#pragma unroll
    for (int i = 0; i < HH / 4; ++i)
      *(float4*)&wv[4 * i] = ((const float4*)(W1 + jp * HH))[i];
    float acc = b1[jp];
#pragma unroll
    for (int k = 0; k < HH; ++k)
      acc += readlane_f(hj, k) * wv[k];
    float val = fmaxf(acc, 0.f) * W2[jp];
    val += __shfl_down(val, 16, 32);
    val += __shfl_down(val, 8, 32);
    val += __shfl_down(val, 4, 32);
    val += __shfl_down(val, 2, 32);
    val += __shfl_down(val, 1, 32);
    if (jp == 0) out[half * (BB * NN) + seq] = val + b2[0];
  }
}

// ---------------- launch -----------------------------------------------------
extern "C" void kernel_launch(void* const* d_in, const int* in_sizes, int n_in,
                              void* d_out, int out_size, void* d_ws, size_t ws_size,
                              hipStream_t stream) {
  const float* x       = (const float*)d_in[0];
  const int*   ei      = (const int*)d_in[1];
  const float* in_W    = (const float*)d_in[2];
  const float* in_b    = (const float*)d_in[3];
  const float* gat_Wl  = (const float*)d_in[4];
  const float* gat_bl  = (const float*)d_in[5];
  const float* gat_Wr  = (const float*)d_in[6];
  const float* gat_br  = (const float*)d_in[7];
  const float* gat_att = (const float*)d_in[8];
  const float* gat_bias= (const float*)d_in[9];
  const float* gru_Wih = (const float*)d_in[10];
  const float* gru_Whh = (const float*)d_in[11];
  const float* gru_bih = (const float*)d_in[12];
  const float* gru_bhh = (const float*)d_in[13];
  const float* oh_W1   = (const float*)d_in[14];
  const float* oh_b1   = (const float*)d_in[15];
  const float* oh_W2   = (const float*)d_in[16];
  const float* oh_b2   = (const float*)d_in[17];
  const float* dh_W1   = (const float*)d_in[18];
  const float* dh_b1   = (const float*)d_in[19];
  const float* dh_W2   = (const float*)d_in[20];
  const float* dh_b2   = (const float*)d_in[21];
  float* out = (float*)d_out;

  char* ws = (char*)d_ws;
  size_t hfloats = (size_t)BB * SS * NN * HH;           // 8.39M floats
  float* hbuf = (float*)ws;
  size_t off_csr = hfloats * sizeof(float);
  size_t off_buf = off_csr + (160 + 2 * ET) * sizeof(int);
  off_buf = (off_buf + 255) & ~(size_t)255;             // 256B align
  int* csr_off = (int*)(ws + off_csr);
  int* csr_src = csr_off + 160;
  int* csr_tgt = csr_src + ET;
  float* xlbuf = (float*)(ws + off_buf);
  float* xrbuf = xlbuf + hfloats;
  size_t need_gat = off_buf + 2 * hfloats * sizeof(float);
  bool big_gat = (ws_size >= need_gat);
  // gi buffer overlays xl/xr (dead after the GAT layers): RT*192 floats
  float* gibuf = (float*)(ws + off_buf);
  size_t need_gru = off_buf + (size_t)RT * 192 * sizeof(float);  // ~134 MB
  bool big_gru = (ws_size >= need_gru);

  setup_csr_kernel<<<1, 256, 0, stream>>>(ei, csr_off, csr_src, csr_tgt);
  input_proj_kernel<<<(BB * SS * NN) / (4 * 32), 256, 0, stream>>>(x, in_W, in_b, hbuf);
  for (int l = 0; l < LLAYERS; ++l) {
    if (big_gat) {
      xlxr_kernel<<<RT / 64, 128, 0, stream>>>(
          hbuf, gat_Wl + l * HH * HH, gat_bl + l * HH,
          gat_Wr + l * HH * HH, gat_br + l * HH, xlbuf, xrbuf);
      gat_edge_kernel<<<BB * SS, 256, 0, stream>>>(
          xlbuf, xrbuf, hbuf, csr_off, csr_src, csr_tgt,
          gat_att + l * HH, gat_bias + l * HH);
    } else {
      gat_fused_kernel<<<BB * SS, 256, 0, stream>>>(
          hbuf, hbuf, csr_off, csr_src, csr_tgt,
          gat_Wl + l * HH * HH, gat_bl + l * HH,
          gat_Wr + l * HH * HH, gat_br + l * HH,
          gat_att + l * HH, gat_bias + l * HH);
    }
  }
  if (big_gru) {
    gi_proj_kernel<<<RT / 64, 192, 0, stream>>>(hbuf, gru_Wih, gru_bih, gibuf);
    gru_rec_kernel<<<BB * NN, 64, 0, stream>>>(
        gibuf, gru_Whh, gru_bhh,
        oh_W1, oh_b1, oh_W2, oh_b2, dh_W1, dh_b1, dh_W2, dh_b2, out);
  } else {
    gru_fused_kernel<<<BB * NN, 192, 0, stream>>>(
        hbuf, gru_Wih, gru_Whh, gru_bih, gru_bhh,
        oh_W1, oh_b1, oh_W2, oh_b2, dh_W1, dh_b1, dh_W2, dh_b2, out);
  }
}